// Round 2
// baseline (161.762 us; speedup 1.0000x reference)
//
#include <hip/hip_runtime.h>
#include <cstdint>

// ---------------------------------------------------------------------------
// MoDBlock: B=2, T=2048, C=512, E=2, NH=8, hs=64, k=1024 (hardcoded).
// Output: out [B,T,C] f32 (2097152) + loss (1).
// ---------------------------------------------------------------------------

#define DI __device__ __forceinline__

typedef __bf16 bf16x8 __attribute__((ext_vector_type(8)));
typedef float  f32x4  __attribute__((ext_vector_type(4)));
typedef short  s16x4  __attribute__((ext_vector_type(4)));

DI uint16_t f2bf(float f) {
    union { float f; uint32_t u; } v; v.f = f;
    uint32_t u = v.u;
    uint32_t r = (u + 0x7FFFu + ((u >> 16) & 1u)) >> 16;   // RNE; finite inputs only
    return (uint16_t)r;
}

DI f32x4 mfma16(bf16x8 a, bf16x8 b, f32x4 c) {
    return __builtin_amdgcn_mfma_f32_16x16x32_bf16(a, b, c, 0, 0, 0);
}

#if __has_builtin(__builtin_amdgcn_mfma_f32_16x16x16bf16_1k)
#define HAVE_MFMA_K16 1
DI f32x4 mfma_k16(s16x4 a, s16x4 b, f32x4 c) {
    return __builtin_amdgcn_mfma_f32_16x16x16bf16_1k(a, b, c, 0, 0, 0);
}
#else
#define HAVE_MFMA_K16 0
#endif

// ---- workspace layout (bytes) ----
constexpr size_t OFF_LOGITS = 0;                                // 4096 f32
constexpr size_t OFF_PL     = OFF_LOGITS + 4096 * 4;            // 4096 f32
constexpr size_t OFF_MASK   = OFF_PL     + 4096 * 4;            // 4096 int
constexpr size_t OFF_POSMAP = OFF_MASK   + 4096 * 4;            // 4096 int
constexpr size_t OFF_IDX    = OFF_POSMAP + 4096 * 4;            // 2048 int
constexpr size_t OFF_WSEL   = OFF_IDX    + 2048 * 4;            // 2048 f32
constexpr size_t OFF_GATE   = OFF_WSEL   + 2048 * 4;            // 2048*2 f32
constexpr size_t OFF_SELBF  = OFF_GATE   + 4096 * 4;            // 2048*512 bf16
constexpr size_t OFF_WQKVT  = OFF_SELBF  + 2048 * 512 * 2;      // [2048][512] bf16
constexpr size_t OFF_WPROJT = OFF_WQKVT  + 2048 * 512 * 2;      // [512][512] bf16
constexpr size_t OFF_QKVRAW = OFF_WPROJT + 512 * 512 * 2;       // 2048*2048 f32
constexpr size_t OFF_QH     = OFF_QKVRAW + (size_t)2048 * 2048 * 4; // [B,E,NH,k,64] bf16
constexpr size_t OFF_KH     = OFF_QH     + (size_t)2097152 * 2;     // [B,NH,k,64] bf16
constexpr size_t OFF_VT     = OFF_KH     + (size_t)1048576 * 2;     // [B,NH,64,k] bf16
constexpr size_t OFF_YBF    = OFF_VT     + (size_t)1048576 * 2;     // [B,E,k,512] bf16
constexpr size_t OFF_YPROJ  = OFF_YBF    + (size_t)4096 * 512 * 2;  // [B,E,k,512] f32

// ---------------------------------------------------------------------------
// 1. router logits (f64 accum, top-k boundary safety) + predictor logits.
__global__ void k_router(const float* __restrict__ x, const float* __restrict__ wr,
                         const float* __restrict__ wp,
                         float* __restrict__ logits, float* __restrict__ pl) {
    int wid  = (blockIdx.x * blockDim.x + threadIdx.x) >> 6;
    int lane = threadIdx.x & 63;
    if (wid >= 4096) return;
    const float* xr = x + (size_t)wid * 512;
    double s = 0.0; float sp = 0.f;
#pragma unroll
    for (int j = 0; j < 8; j++) {
        int c = lane + 64 * j;
        float xv = xr[c];
        s  += (double)xv * (double)wr[c];
        sp += xv * wp[c];
    }
    for (int m = 1; m < 64; m <<= 1) { s += __shfl_xor(s, m); sp += __shfl_xor(sp, m); }
    if (lane == 0) { logits[wid] = (float)s; pl[wid] = sp; }
}

// 2. rank: count of strictly-greater (or equal with smaller index) -> mask
__global__ void k_rank(const float* __restrict__ logits, int* __restrict__ mask) {
    int wid  = (blockIdx.x * blockDim.x + threadIdx.x) >> 6;
    int lane = threadIdx.x & 63;
    if (wid >= 4096) return;
    int b = wid >> 11, t = wid & 2047;
    const float* lb = logits + b * 2048;
    float v = lb[t];
    int cnt = 0;
    for (int j = 0; j < 32; j++) {
        int tp = lane + 64 * j;
        float lv = lb[tp];
        bool pred = (lv > v) || (lv == v && tp < t);
        cnt += __popcll(__ballot(pred));
    }
    if (lane == 0) mask[wid] = (cnt < 1024) ? 1 : 0;
}

// 3. wave-scan selection: idx (temporal order), wsel, posmap. 1 block/batch.
__global__ void k_select(const float* __restrict__ logits, const int* __restrict__ mask,
                         int* __restrict__ idx, float* __restrict__ wsel,
                         int* __restrict__ posmap) {
    __shared__ int wsum[16], woff[16];
    int b = blockIdx.x, tid = threadIdx.x, lane = tid & 63, w = tid >> 6;
    int t0 = tid * 2, t1 = tid * 2 + 1;
    int m0 = mask[b * 2048 + t0], m1 = mask[b * 2048 + t1];
    int s = m0 + m1;
    int sc = s;
    for (int off = 1; off < 64; off <<= 1) {
        int v = __shfl_up(sc, off);
        if (lane >= off) sc += v;
    }
    if (lane == 63) wsum[w] = sc;
    __syncthreads();
    if (tid < 16) {
        int acc = 0;
        for (int j = 0; j < tid; j++) acc += wsum[j];
        woff[tid] = acc;
    }
    __syncthreads();
    int excl = woff[w] + sc - s;
    int p0 = excl, p1 = excl + m0;
    if (m0) {
        idx[b * 1024 + p0] = t0;
        float v = logits[b * 2048 + t0];
        wsel[b * 1024 + p0] = 1.f / (1.f + __expf(-v));
    }
    posmap[b * 2048 + t0] = m0 ? p0 : -1;
    if (m1) {
        idx[b * 1024 + p1] = t1;
        float v = logits[b * 2048 + t1];
        wsel[b * 1024 + p1] = 1.f / (1.f + __expf(-v));
    }
    posmap[b * 2048 + t1] = m1 ? p1 : -1;
}

// 4. weight transpose+cast via LDS 64x64 tile: coalesced both sides.
__global__ __launch_bounds__(256) void k_castw(const float* __restrict__ Wq,
                                               const float* __restrict__ Wkv,
                                               const float* __restrict__ Wp,
                                               uint16_t* __restrict__ Wqkvt,
                                               uint16_t* __restrict__ Wprojt) {
    __shared__ float tile[64][65];
    int blk = blockIdx.x, tid = threadIdx.x;
    const float* src; uint16_t* dst; int n0, c0, ldn;
    if (blk < 256) {                   // qkv: dest [2048][512]
        int tn = blk & 31, tc = blk >> 5;
        n0 = tn * 64; c0 = tc * 64; ldn = 1024;
        if (n0 < 1024) { src = Wq; } else { src = Wkv; n0 -= 1024; }
        dst = Wqkvt + (size_t)(tn * 64) * 512 + c0;
    } else {                           // proj: dest [512][512]
        int j = blk - 256; int tn = j & 7, tc = j >> 3;
        n0 = tn * 64; c0 = tc * 64; ldn = 512;
        src = Wp; dst = Wprojt + (size_t)n0 * 512 + c0;
    }
    int nl = tid & 63, cb = tid >> 6;
#pragma unroll
    for (int p = 0; p < 16; p++) {
        int cl_ = p * 4 + cb;
        tile[cl_][nl] = src[(size_t)(c0 + cl_) * ldn + n0 + nl];
    }
    __syncthreads();
    int cp = tid & 31, nb = tid >> 5;
#pragma unroll
    for (int p = 0; p < 8; p++) {
        int nl2 = p * 8 + nb;
        uint32_t pk = (uint32_t)f2bf(tile[cp * 2][nl2]) |
                      ((uint32_t)f2bf(tile[cp * 2 + 1][nl2]) << 16);
        *(uint32_t*)&dst[(size_t)nl2 * 512 + cp * 2] = pk;
    }
}

// 5. gather selected rows -> bf16, gate = softmax(sel @ W_gate)
__global__ void k_gather_gate(const float* __restrict__ x, const int* __restrict__ idx,
                              const float* __restrict__ Wg,
                              uint16_t* __restrict__ selbf, float* __restrict__ gate) {
    __shared__ float red0[4], red1[4];
    int blk = blockIdx.x; int b = blk >> 10;
    int tid = threadIdx.x, lane = tid & 63, w = tid >> 6;
    int t = idx[blk];
    const float* xr = x + ((size_t)b * 2048 + t) * 512;
    int c = tid * 2;
    float v0 = xr[c], v1 = xr[c + 1];
    uint32_t pk = (uint32_t)f2bf(v0) | ((uint32_t)f2bf(v1) << 16);
    ((uint32_t*)(selbf + (size_t)blk * 512))[tid] = pk;
    float g0 = v0 * Wg[c * 2]     + v1 * Wg[(c + 1) * 2];
    float g1 = v0 * Wg[c * 2 + 1] + v1 * Wg[(c + 1) * 2 + 1];
    for (int m = 1; m < 64; m <<= 1) { g0 += __shfl_xor(g0, m); g1 += __shfl_xor(g1, m); }
    if (lane == 0) { red0[w] = g0; red1[w] = g1; }
    __syncthreads();
    if (tid == 0) {
        float a = red0[0] + red0[1] + red0[2] + red0[3];
        float bq = red1[0] + red1[1] + red1[2] + red1[3];
        float mx = fmaxf(a, bq);
        float ea = __expf(a - mx), eb = __expf(bq - mx), s = ea + eb;
        gate[blk * 2] = ea / s; gate[blk * 2 + 1] = eb / s;
    }
}

// 6. bf16 MFMA GEMM: C[M,N] f32 = A[M,K]bf16 @ Bt[N,K]^T. 128x128 tile, BK=32.
__global__ __launch_bounds__(256) void k_gemm(const uint16_t* __restrict__ A,
                                              const uint16_t* __restrict__ Bt,
                                              float* __restrict__ Cc,
                                              int M, int N, int Kd) {
    __shared__ uint16_t As[128 * 40], Bs[128 * 40];
    int tid = threadIdx.x, lane = tid & 63, w = tid >> 6;
    int m0 = blockIdx.x * 128, n0 = blockIdx.y * 128;
    int wr = (w >> 1) * 64, wc = (w & 1) * 64;
    f32x4 acc[4][4];
#pragma unroll
    for (int mt = 0; mt < 4; mt++)
#pragma unroll
        for (int nt = 0; nt < 4; nt++)
#pragma unroll
            for (int r = 0; r < 4; r++) acc[mt][nt][r] = 0.f;
    int arow = tid >> 2, akg = tid & 3;
    int K8 = Kd >> 3;
    const bf16x8* A8 = (const bf16x8*)A;
    const bf16x8* B8 = (const bf16x8*)Bt;
    for (int ks = 0; ks < Kd; ks += 32) {
        __syncthreads();
        int kc = (ks >> 3) + akg;
        bf16x8 va0 = A8[(size_t)(m0 + arow) * K8 + kc];
        bf16x8 va1 = A8[(size_t)(m0 + arow + 64) * K8 + kc];
        bf16x8 vb0 = B8[(size_t)(n0 + arow) * K8 + kc];
        bf16x8 vb1 = B8[(size_t)(n0 + arow + 64) * K8 + kc];
        *(bf16x8*)&As[arow * 40 + akg * 8] = va0;
        *(bf16x8*)&As[(arow + 64) * 40 + akg * 8] = va1;
        *(bf16x8*)&Bs[arow * 40 + akg * 8] = vb0;
        *(bf16x8*)&Bs[(arow + 64) * 40 + akg * 8] = vb1;
        __syncthreads();
        bf16x8 af[4], bfr[4];
#pragma unroll
        for (int t = 0; t < 4; t++) {
            af[t]  = *(const bf16x8*)&As[(wr + t * 16 + (lane & 15)) * 40 + (lane >> 4) * 8];
            bfr[t] = *(const bf16x8*)&Bs[(wc + t * 16 + (lane & 15)) * 40 + (lane >> 4) * 8];
        }
#pragma unroll
        for (int mt = 0; mt < 4; mt++)
#pragma unroll
            for (int nt = 0; nt < 4; nt++)
                acc[mt][nt] = mfma16(af[mt], bfr[nt], acc[mt][nt]);
    }
    int r0 = (lane >> 4) * 4, cl = lane & 15;
#pragma unroll
    for (int mt = 0; mt < 4; mt++)
#pragma unroll
        for (int nt = 0; nt < 4; nt++)
#pragma unroll
            for (int r = 0; r < 4; r++) {
                int row = m0 + wr + mt * 16 + r0 + r;
                int col = n0 + wc + nt * 16 + cl;
                Cc[(size_t)row * N + col] = acc[mt][nt][r];
            }
}

// 7. RMSNorm + RoPE -> head-layout bf16 Q,K and transposed V
__global__ void k_norm_rope(const float* __restrict__ qkv, const float* __restrict__ lnw,
                            uint16_t* __restrict__ Qh, uint16_t* __restrict__ Kh,
                            uint16_t* __restrict__ Vt) {
    __shared__ float red[4];
    int blk = blockIdx.x; int b = blk >> 10, i = blk & 1023;
    int tid = threadIdx.x, lane = tid & 63, w = tid >> 6;
    const float* row = qkv + (size_t)blk * 2048;
    int c0 = tid * 2;
    int d0 = c0 & 63, head = c0 >> 6;
    int j0 = d0 & 31, j1 = (d0 + 1) & 31;
    const float LN1E4_64 = 0.14391156831212787f;   // ln(10000)/64
    float fi = (float)i;
    float ang0 = fi * __expf(-(float)(4 * j0 + 1) * LN1E4_64);
    float ang1 = fi * __expf(-(float)(4 * j1 + 1) * LN1E4_64);
    float c_0 = cosf(ang0), s_0 = sinf(ang0);
    float c_1 = cosf(ang1), s_1 = sinf(ang1);
    float g0 = lnw[c0], g1 = lnw[c0 + 1];
    for (int which = 0; which < 3; which++) {        // q(e=0), q(e=1), k
        int off = which * 512;
        float u0 = row[off + c0], u1 = row[off + c0 + 1];
        float ss = u0 * u0 + u1 * u1;
        for (int m = 1; m < 64; m <<= 1) ss += __shfl_xor(ss, m);
        __syncthreads();
        if (lane == 0) red[w] = ss;
        __syncthreads();
        float tot = red[0] + red[1] + red[2] + red[3];
        float rinv = rsqrtf(tot * (1.0f / 512.0f) + 1e-6f);
        float n0 = u0 * rinv * g0, n1 = u1 * rinv * g1;
        float r0 = n0 * c_0 - n1 * s_0;              // even dim
        float r1 = n1 * c_1 + n0 * s_1;              // odd dim (different angle!)
        uint32_t pk = (uint32_t)f2bf(r0) | ((uint32_t)f2bf(r1) << 16);
        if (which < 2) {
            uint16_t* dstp = Qh + ((size_t)((b * 2 + which) * 8 + head) * 1024 + i) * 64 + d0;
            *(uint32_t*)dstp = pk;
        } else {
            uint16_t* dstp = Kh + ((size_t)(b * 8 + head) * 1024 + i) * 64 + d0;
            *(uint32_t*)dstp = pk;
        }
    }
    {   // v: no norm, no rope; store transposed [d][k]
        float u0 = row[1536 + c0], u1 = row[1536 + c0 + 1];
        Vt[((size_t)(b * 8 + head) * 64 + d0) * 1024 + i]     = f2bf(u0);
        Vt[((size_t)(b * 8 + head) * 64 + d0 + 1) * 1024 + i] = f2bf(u1);
    }
}

// 8. causal flash attention, swapped-operand QK^T (reduction axis lane-local).
//    wave = 16 q rows; D[kv][q]: col=q=lane&15, row=kv=gp*4+r.
//    PV consumes P directly as 16x16x16 B-fragment: no LDS, no shuffles.
__global__ __launch_bounds__(256) void k_attn(const uint16_t* __restrict__ Qh,
                                              const uint16_t* __restrict__ Kh,
                                              const uint16_t* __restrict__ Vt,
                                              uint16_t* __restrict__ ybf) {
#if !HAVE_MFMA_K16
    __shared__ uint16_t Pl[4][16 * 80];              // fallback: per-wave P tile
#endif
    int blk = blockIdx.x;
    int qb = blk & 15, h = (blk >> 4) & 7, e = (blk >> 7) & 1, b = blk >> 8;
    int tid = threadIdx.x, lane = tid & 63, w = tid >> 6;
    int qw = qb * 64 + w * 16;
    const uint16_t* Qb = Qh + ((size_t)((b * 2 + e) * 8 + h) * 1024 + qw) * 64;
    const uint16_t* Kb = Kh + (size_t)(b * 8 + h) * 1024 * 64;
    const uint16_t* Vb = Vt + (size_t)(b * 8 + h) * 64 * 1024;
    int cl = lane & 15, gp = lane >> 4;
    bf16x8 qf0 = *(const bf16x8*)&Qb[cl * 64 + gp * 8];
    bf16x8 qf1 = *(const bf16x8*)&Qb[cl * 64 + 32 + gp * 8];
    f32x4 o[4];
#pragma unroll
    for (int dt = 0; dt < 4; dt++)
#pragma unroll
        for (int r = 0; r < 4; r++) o[dt][r] = 0.f;
    float m = -INFINITY, ls = 0.f;
    int qa = qw + cl;

    for (int jt = 0; jt <= qw; jt += 64) {
        f32x4 s[4];
#pragma unroll
        for (int t = 0; t < 4; t++)
#pragma unroll
            for (int r = 0; r < 4; r++) s[t][r] = 0.f;
#pragma unroll
        for (int t = 0; t < 4; t++) {
            const uint16_t* kr = &Kb[(size_t)(jt + t * 16 + cl) * 64 + gp * 8];
            bf16x8 k0 = *(const bf16x8*)kr;
            bf16x8 k1 = *(const bf16x8*)(kr + 32);
            s[t] = mfma16(k0, qf0, s[t]);
            s[t] = mfma16(k1, qf1, s[t]);
        }
        if (jt + 63 > qw) {                          // boundary tile: causal mask
#pragma unroll
            for (int t = 0; t < 4; t++) {
                int kvb = jt + t * 16 + gp * 4;
#pragma unroll
                for (int r = 0; r < 4; r++)
                    s[t][r] = (kvb + r <= qa) ? s[t][r] * 0.125f : -INFINITY;
            }
        } else {
#pragma unroll
            for (int t = 0; t < 4; t++)
#pragma unroll
                for (int r = 0; r < 4; r++) s[t][r] *= 0.125f;
        }
        // online softmax: all 16 values for q=cl are local; 2 shfl over gp groups
        float tmax = fmaxf(fmaxf(fmaxf(s[0][0], s[0][1]), fmaxf(s[0][2], s[0][3])),
                           fmaxf(fmaxf(s[1][0], s[1][1]), fmaxf(s[1][2], s[1][3])));
        tmax = fmaxf(tmax,
               fmaxf(fmaxf(fmaxf(s[2][0], s[2][1]), fmaxf(s[2][2], s[2][3])),
                     fmaxf(fmaxf(s[3][0], s[3][1]), fmaxf(s[3][2], s[3][3]))));
        tmax = fmaxf(tmax, __shfl_xor(tmax, 16));
        tmax = fmaxf(tmax, __shfl_xor(tmax, 32));
        float mn = fmaxf(m, tmax);
        float sc = __expf(m - mn);
        m = mn;
        float lsum = 0.f;
#pragma unroll
        for (int t = 0; t < 4; t++)
#pragma unroll
            for (int r = 0; r < 4; r++) {
                float p = __expf(s[t][r] - mn);
                s[t][r] = p;
                lsum += p;
            }
        lsum += __shfl_xor(lsum, 16);
        lsum += __shfl_xor(lsum, 32);
        ls = ls * sc + lsum;
#pragma unroll
        for (int dt = 0; dt < 4; dt++) o[dt] *= sc;
#if HAVE_MFMA_K16
        s16x4 pb[4];
#pragma unroll
        for (int t = 0; t < 4; t++)
#pragma unroll
            for (int r = 0; r < 4; r++) pb[t][r] = (short)f2bf(s[t][r]);
#pragma unroll
        for (int dt = 0; dt < 4; dt++)
#pragma unroll
            for (int t = 0; t < 4; t++) {
                s16x4 va = *(const s16x4*)&Vb[(size_t)(dt * 16 + cl) * 1024 + jt + t * 16 + gp * 4];
                o[dt] = mfma_k16(va, pb[t], o[dt]);
            }
#else
        uint16_t* Pw = Pl[w];
#pragma unroll
        for (int t = 0; t < 4; t++)
#pragma unroll
            for (int r = 0; r < 4; r++)
                Pw[cl * 80 + t * 16 + gp * 4 + r] = f2bf(s[t][r]);
#pragma unroll
        for (int h2 = 0; h2 < 2; h2++) {
            bf16x8 pB = *(const bf16x8*)&Pw[cl * 80 + h2 * 32 + gp * 8];
#pragma unroll
            for (int dt = 0; dt < 4; dt++) {
                bf16x8 va = *(const bf16x8*)&Vb[(size_t)(dt * 16 + cl) * 1024 + jt + h2 * 32 + gp * 8];
                o[dt] = mfma16(va, pB, o[dt]);
            }
        }
#endif
    }
    float inv = 1.f / ls;
    uint16_t* yb = ybf + ((size_t)(b * 2 + e) * 1024 + qw) * 512 + h * 64;
#pragma unroll
    for (int dt = 0; dt < 4; dt++) {
        uint16_t pk[4];
#pragma unroll
        for (int r = 0; r < 4; r++) pk[r] = f2bf(o[dt][r] * inv);
        *(uint2*)&yb[(size_t)cl * 512 + dt * 16 + gp * 4] = *(const uint2*)pk;
    }
}

// 9. epilogue: out = x (+ gated expert mix on selected rows)
__global__ void k_epilogue(const float* __restrict__ x, const int* __restrict__ posmap,
                           const float* __restrict__ yproj, const float* __restrict__ gate,
                           const float* __restrict__ wsel, float* __restrict__ out) {
    int row = blockIdx.x;                 // 4096
    int b = row >> 11;
    int tid = threadIdx.x;                // 128
    const float4* xr = (const float4*)(x + (size_t)row * 512);
    float4* orow = (float4*)(out + (size_t)row * 512);
    float4 v = xr[tid];
    int pos = posmap[row];
    if (pos >= 0) {
        int bk = b * 1024 + pos;
        float wv = wsel[bk], g0 = gate[bk * 2], g1 = gate[bk * 2 + 1];
        const float4* y0 = (const float4*)(yproj + ((size_t)(b * 2) * 1024 + pos) * 512);
        const float4* y1 = (const float4*)(yproj + ((size_t)(b * 2 + 1) * 1024 + pos) * 512);
        float4 a = y0[tid], c = y1[tid];
        v.x += wv * (g0 * a.x + g1 * c.x);
        v.y += wv * (g0 * a.y + g1 * c.y);
        v.z += wv * (g0 * a.z + g1 * c.z);
        v.w += wv * (g0 * a.w + g1 * c.w);
    }
    orow[tid] = v;
}

// 10. BCE loss from precomputed predictor logits. single block.
__global__ void k_loss(const float* __restrict__ pl, const int* __restrict__ mask,
                       float* __restrict__ outloss) {
    __shared__ float red[16];
    int tid = threadIdx.x;                // 1024
    float s = 0.f;
#pragma unroll
    for (int j = 0; j < 4; j++) {
        int i = tid * 4 + j;
        float p = pl[i];
        float tgt = (float)mask[i];
        s += fmaxf(p, 0.f) - p * tgt + log1pf(__expf(-fabsf(p)));
    }
    for (int mm = 1; mm < 64; mm <<= 1) s += __shfl_xor(s, mm);
    int lane = tid & 63, w = tid >> 6;
    if (lane == 0) red[w] = s;
    __syncthreads();
    if (tid == 0) {
        float t = 0.f;
        for (int q = 0; q < 16; q++) t += red[q];
        outloss[0] = t * (1.0f / 4096.0f);
    }
}

// ---------------------------------------------------------------------------
extern "C" void kernel_launch(void* const* d_in, const int* in_sizes, int n_in,
                              void* d_out, int out_size, void* d_ws, size_t ws_size,
                              hipStream_t stream) {
    const float* x        = (const float*)d_in[0];
    const float* W_router = (const float*)d_in[1];
    const float* W_q      = (const float*)d_in[2];
    const float* W_kv     = (const float*)d_in[3];
    const float* W_proj   = (const float*)d_in[4];
    const float* ln_w     = (const float*)d_in[5];
    const float* W_gate   = (const float*)d_in[6];
    const float* W_pred   = (const float*)d_in[7];

    char* ws = (char*)d_ws;
    float*    logits = (float*)   (ws + OFF_LOGITS);
    float*    pl     = (float*)   (ws + OFF_PL);
    int*      mask   = (int*)     (ws + OFF_MASK);
    int*      posmap = (int*)     (ws + OFF_POSMAP);
    int*      idx    = (int*)     (ws + OFF_IDX);
    float*    wsel   = (float*)   (ws + OFF_WSEL);
    float*    gate   = (float*)   (ws + OFF_GATE);
    uint16_t* selbf  = (uint16_t*)(ws + OFF_SELBF);
    uint16_t* Wqkvt  = (uint16_t*)(ws + OFF_WQKVT);
    uint16_t* Wprojt = (uint16_t*)(ws + OFF_WPROJT);
    float*    qkvraw = (float*)   (ws + OFF_QKVRAW);
    uint16_t* Qh     = (uint16_t*)(ws + OFF_QH);
    uint16_t* Kh     = (uint16_t*)(ws + OFF_KH);
    uint16_t* Vt     = (uint16_t*)(ws + OFF_VT);
    uint16_t* ybf    = (uint16_t*)(ws + OFF_YBF);
    float*    yproj  = (float*)   (ws + OFF_YPROJ);
    float*    out    = (float*)d_out;

    k_castw      <<<320, 256, 0, stream>>>(W_q, W_kv, W_proj, Wqkvt, Wprojt);
    k_router     <<<1024, 256, 0, stream>>>(x, W_router, W_pred, logits, pl);
    k_rank       <<<1024, 256, 0, stream>>>(logits, mask);
    k_select     <<<2, 1024, 0, stream>>>(logits, mask, idx, wsel, posmap);
    k_gather_gate<<<2048, 256, 0, stream>>>(x, idx, W_gate, selbf, gate);
    k_gemm       <<<dim3(16, 16), 256, 0, stream>>>(selbf, Wqkvt, qkvraw, 2048, 2048, 512);
    k_norm_rope  <<<2048, 256, 0, stream>>>(qkvraw, ln_w, Qh, Kh, Vt);
    k_attn       <<<512, 256, 0, stream>>>(Qh, Kh, Vt, ybf);
    k_gemm       <<<dim3(32, 4), 256, 0, stream>>>(ybf, Wprojt, yproj, 4096, 512, 512);
    k_epilogue   <<<4096, 128, 0, stream>>>(x, posmap, yproj, gate, wsel, out);
    k_loss       <<<1, 1024, 0, stream>>>(pl, mask, out + 2097152);
}

// Round 3
// 120.356 us; speedup vs baseline: 1.3440x; 1.3440x over previous
//
#include <hip/hip_runtime.h>
#include <cstdint>

// ---------------------------------------------------------------------------
// MoDBlock: B=2, T=2048, C=512, E=2, NH=8, hs=64, k=1024 (hardcoded).
// Output: out [B,T,C] f32 (2097152) + loss (1).
// ---------------------------------------------------------------------------

#define DI __device__ __forceinline__

typedef __bf16 bf16x8 __attribute__((ext_vector_type(8)));
typedef float  f32x4  __attribute__((ext_vector_type(4)));
typedef short  s16x4  __attribute__((ext_vector_type(4)));
typedef short  s16x8  __attribute__((ext_vector_type(8)));

DI uint16_t f2bf(float f) {
    union { float f; uint32_t u; } v; v.f = f;
    uint32_t u = v.u;
    uint32_t r = (u + 0x7FFFu + ((u >> 16) & 1u)) >> 16;   // RNE; finite inputs only
    return (uint16_t)r;
}
DI float bf2f(uint32_t lo16) {
    union { uint32_t u; float f; } v; v.u = lo16 << 16; return v.f;
}

DI f32x4 mfma16(bf16x8 a, bf16x8 b, f32x4 c) {
    return __builtin_amdgcn_mfma_f32_16x16x32_bf16(a, b, c, 0, 0, 0);
}
DI f32x4 mfma_k16(s16x4 a, s16x4 b, f32x4 c) {
    return __builtin_amdgcn_mfma_f32_16x16x16bf16_1k(a, b, c, 0, 0, 0);
}

// ---- workspace layout (bytes) ----
constexpr size_t OFF_LOGITS = 0;                                // 4096 f32
constexpr size_t OFF_PL     = OFF_LOGITS + 4096 * 4;            // 4096 f32
constexpr size_t OFF_MASK   = OFF_PL     + 4096 * 4;            // 4096 int
constexpr size_t OFF_POSMAP = OFF_MASK   + 4096 * 4;            // 4096 int
constexpr size_t OFF_IDX    = OFF_POSMAP + 4096 * 4;            // 2048 int
constexpr size_t OFF_WSEL   = OFF_IDX    + 2048 * 4;            // 2048 f32
constexpr size_t OFF_GATE   = OFF_WSEL   + 2048 * 4;            // 2048*2 f32
constexpr size_t OFF_SELBF  = OFF_GATE   + 4096 * 4;            // 2048*512 bf16
constexpr size_t OFF_WQKVT  = OFF_SELBF  + 2048 * 512 * 2;      // [2048][512] bf16
constexpr size_t OFF_WPROJT = OFF_WQKVT  + 2048 * 512 * 2;      // [512][512] bf16
constexpr size_t OFF_QKVRAW = OFF_WPROJT + 512 * 512 * 2;       // 2048*2048 f32
// attention partials ALIAS qkvraw (dead after k_norm_rope):
constexpr size_t OFF_PO     = OFF_QKVRAW;                       // 32*1024*2*64 bf16 = 8MB
constexpr size_t OFF_PML    = OFF_PO + (size_t)32 * 1024 * 2 * 64 * 2; // 32*1024*2 float2
constexpr size_t OFF_QH     = OFF_QKVRAW + (size_t)2048 * 2048 * 4; // [B,E,NH,k,64] bf16
constexpr size_t OFF_KH     = OFF_QH     + (size_t)2097152 * 2;     // [B,NH,k,64] bf16
constexpr size_t OFF_VT     = OFF_KH     + (size_t)1048576 * 2;     // [B,NH,64,k] bf16 (kv-swizzled)
constexpr size_t OFF_YBF    = OFF_VT     + (size_t)1048576 * 2;     // [B,E,k,512] bf16
constexpr size_t OFF_YPROJ  = OFF_YBF    + (size_t)4096 * 512 * 2;  // [B,E,k,512] f32

// ---------------------------------------------------------------------------
// 1. router logits (f64 accum, top-k boundary safety) + predictor logits.
__global__ void k_router(const float* __restrict__ x, const float* __restrict__ wr,
                         const float* __restrict__ wp,
                         float* __restrict__ logits, float* __restrict__ pl) {
    int wid  = (blockIdx.x * blockDim.x + threadIdx.x) >> 6;
    int lane = threadIdx.x & 63;
    if (wid >= 4096) return;
    const float* xr = x + (size_t)wid * 512;
    double s = 0.0; float sp = 0.f;
#pragma unroll
    for (int j = 0; j < 8; j++) {
        int c = lane + 64 * j;
        float xv = xr[c];
        s  += (double)xv * (double)wr[c];
        sp += xv * wp[c];
    }
    for (int m = 1; m < 64; m <<= 1) { s += __shfl_xor(s, m); sp += __shfl_xor(sp, m); }
    if (lane == 0) { logits[wid] = (float)s; pl[wid] = sp; }
}

// 2. rank: count of strictly-greater (or equal with smaller index) -> mask
__global__ void k_rank(const float* __restrict__ logits, int* __restrict__ mask) {
    int wid  = (blockIdx.x * blockDim.x + threadIdx.x) >> 6;
    int lane = threadIdx.x & 63;
    if (wid >= 4096) return;
    int b = wid >> 11, t = wid & 2047;
    const float* lb = logits + b * 2048;
    float v = lb[t];
    int cnt = 0;
    for (int j = 0; j < 32; j++) {
        int tp = lane + 64 * j;
        float lv = lb[tp];
        bool pred = (lv > v) || (lv == v && tp < t);
        cnt += __popcll(__ballot(pred));
    }
    if (lane == 0) mask[wid] = (cnt < 1024) ? 1 : 0;
}

// 3. wave-scan selection: idx (temporal order), wsel, posmap. 1 block/batch.
__global__ void k_select(const float* __restrict__ logits, const int* __restrict__ mask,
                         int* __restrict__ idx, float* __restrict__ wsel,
                         int* __restrict__ posmap) {
    __shared__ int wsum[16], woff[16];
    int b = blockIdx.x, tid = threadIdx.x, lane = tid & 63, w = tid >> 6;
    int t0 = tid * 2, t1 = tid * 2 + 1;
    int m0 = mask[b * 2048 + t0], m1 = mask[b * 2048 + t1];
    int s = m0 + m1;
    int sc = s;
    for (int off = 1; off < 64; off <<= 1) {
        int v = __shfl_up(sc, off);
        if (lane >= off) sc += v;
    }
    if (lane == 63) wsum[w] = sc;
    __syncthreads();
    if (tid < 16) {
        int acc = 0;
        for (int j = 0; j < tid; j++) acc += wsum[j];
        woff[tid] = acc;
    }
    __syncthreads();
    int excl = woff[w] + sc - s;
    int p0 = excl, p1 = excl + m0;
    if (m0) {
        idx[b * 1024 + p0] = t0;
        float v = logits[b * 2048 + t0];
        wsel[b * 1024 + p0] = 1.f / (1.f + __expf(-v));
    }
    posmap[b * 2048 + t0] = m0 ? p0 : -1;
    if (m1) {
        idx[b * 1024 + p1] = t1;
        float v = logits[b * 2048 + t1];
        wsel[b * 1024 + p1] = 1.f / (1.f + __expf(-v));
    }
    posmap[b * 2048 + t1] = m1 ? p1 : -1;
}

// 4. weight transpose+cast via LDS 64x64 tile: coalesced both sides.
__global__ __launch_bounds__(256) void k_castw(const float* __restrict__ Wq,
                                               const float* __restrict__ Wkv,
                                               const float* __restrict__ Wp,
                                               uint16_t* __restrict__ Wqkvt,
                                               uint16_t* __restrict__ Wprojt) {
    __shared__ float tile[64][65];
    int blk = blockIdx.x, tid = threadIdx.x;
    const float* src; uint16_t* dst; int n0, c0, ldn;
    if (blk < 256) {                   // qkv: dest [2048][512]
        int tn = blk & 31, tc = blk >> 5;
        n0 = tn * 64; c0 = tc * 64; ldn = 1024;
        if (n0 < 1024) { src = Wq; } else { src = Wkv; n0 -= 1024; }
        dst = Wqkvt + (size_t)(tn * 64) * 512 + c0;
    } else {                           // proj: dest [512][512]
        int j = blk - 256; int tn = j & 7, tc = j >> 3;
        n0 = tn * 64; c0 = tc * 64; ldn = 512;
        src = Wp; dst = Wprojt + (size_t)n0 * 512 + c0;
    }
    int nl = tid & 63, cb = tid >> 6;
#pragma unroll
    for (int p = 0; p < 16; p++) {
        int cl_ = p * 4 + cb;
        tile[cl_][nl] = src[(size_t)(c0 + cl_) * ldn + n0 + nl];
    }
    __syncthreads();
    int cp = tid & 31, nb = tid >> 5;
#pragma unroll
    for (int p = 0; p < 8; p++) {
        int nl2 = p * 8 + nb;
        uint32_t pk = (uint32_t)f2bf(tile[cp * 2][nl2]) |
                      ((uint32_t)f2bf(tile[cp * 2 + 1][nl2]) << 16);
        *(uint32_t*)&dst[(size_t)nl2 * 512 + cp * 2] = pk;
    }
}

// 5. gather selected rows -> bf16, gate = softmax(sel @ W_gate)
__global__ void k_gather_gate(const float* __restrict__ x, const int* __restrict__ idx,
                              const float* __restrict__ Wg,
                              uint16_t* __restrict__ selbf, float* __restrict__ gate) {
    __shared__ float red0[4], red1[4];
    int blk = blockIdx.x; int b = blk >> 10;
    int tid = threadIdx.x, lane = tid & 63, w = tid >> 6;
    int t = idx[blk];
    const float* xr = x + ((size_t)b * 2048 + t) * 512;
    int c = tid * 2;
    float v0 = xr[c], v1 = xr[c + 1];
    uint32_t pk = (uint32_t)f2bf(v0) | ((uint32_t)f2bf(v1) << 16);
    ((uint32_t*)(selbf + (size_t)blk * 512))[tid] = pk;
    float g0 = v0 * Wg[c * 2]     + v1 * Wg[(c + 1) * 2];
    float g1 = v0 * Wg[c * 2 + 1] + v1 * Wg[(c + 1) * 2 + 1];
    for (int m = 1; m < 64; m <<= 1) { g0 += __shfl_xor(g0, m); g1 += __shfl_xor(g1, m); }
    if (lane == 0) { red0[w] = g0; red1[w] = g1; }
    __syncthreads();
    if (tid == 0) {
        float a = red0[0] + red0[1] + red0[2] + red0[3];
        float bq = red1[0] + red1[1] + red1[2] + red1[3];
        float mx = fmaxf(a, bq);
        float ea = __expf(a - mx), eb = __expf(bq - mx), s = ea + eb;
        gate[blk * 2] = ea / s; gate[blk * 2 + 1] = eb / s;
    }
}

// 6. bf16 MFMA GEMM: C[M,N] f32 = A[M,K]bf16 @ Bt[N,K]^T. 128x128 tile, BK=32.
__global__ __launch_bounds__(256) void k_gemm(const uint16_t* __restrict__ A,
                                              const uint16_t* __restrict__ Bt,
                                              float* __restrict__ Cc,
                                              int M, int N, int Kd) {
    __shared__ uint16_t As[128 * 40], Bs[128 * 40];
    int tid = threadIdx.x, lane = tid & 63, w = tid >> 6;
    int m0 = blockIdx.x * 128, n0 = blockIdx.y * 128;
    int wr = (w >> 1) * 64, wc = (w & 1) * 64;
    f32x4 acc[4][4];
#pragma unroll
    for (int mt = 0; mt < 4; mt++)
#pragma unroll
        for (int nt = 0; nt < 4; nt++)
#pragma unroll
            for (int r = 0; r < 4; r++) acc[mt][nt][r] = 0.f;
    int arow = tid >> 2, akg = tid & 3;
    int K8 = Kd >> 3;
    const bf16x8* A8 = (const bf16x8*)A;
    const bf16x8* B8 = (const bf16x8*)Bt;
    for (int ks = 0; ks < Kd; ks += 32) {
        __syncthreads();
        int kc = (ks >> 3) + akg;
        bf16x8 va0 = A8[(size_t)(m0 + arow) * K8 + kc];
        bf16x8 va1 = A8[(size_t)(m0 + arow + 64) * K8 + kc];
        bf16x8 vb0 = B8[(size_t)(n0 + arow) * K8 + kc];
        bf16x8 vb1 = B8[(size_t)(n0 + arow + 64) * K8 + kc];
        *(bf16x8*)&As[arow * 40 + akg * 8] = va0;
        *(bf16x8*)&As[(arow + 64) * 40 + akg * 8] = va1;
        *(bf16x8*)&Bs[arow * 40 + akg * 8] = vb0;
        *(bf16x8*)&Bs[(arow + 64) * 40 + akg * 8] = vb1;
        __syncthreads();
        bf16x8 af[4], bfr[4];
#pragma unroll
        for (int t = 0; t < 4; t++) {
            af[t]  = *(const bf16x8*)&As[(wr + t * 16 + (lane & 15)) * 40 + (lane >> 4) * 8];
            bfr[t] = *(const bf16x8*)&Bs[(wc + t * 16 + (lane & 15)) * 40 + (lane >> 4) * 8];
        }
#pragma unroll
        for (int mt = 0; mt < 4; mt++)
#pragma unroll
            for (int nt = 0; nt < 4; nt++)
                acc[mt][nt] = mfma16(af[mt], bfr[nt], acc[mt][nt]);
    }
    int r0 = (lane >> 4) * 4, cl = lane & 15;
#pragma unroll
    for (int mt = 0; mt < 4; mt++)
#pragma unroll
        for (int nt = 0; nt < 4; nt++)
#pragma unroll
            for (int r = 0; r < 4; r++) {
                int row = m0 + wr + mt * 16 + r0 + r;
                int col = n0 + wc + nt * 16 + cl;
                Cc[(size_t)row * N + col] = acc[mt][nt][r];
            }
}

// 7. RMSNorm + RoPE -> head-layout bf16 Q,K and kv-swizzled transposed V
__global__ void k_norm_rope(const float* __restrict__ qkv, const float* __restrict__ lnw,
                            uint16_t* __restrict__ Qh, uint16_t* __restrict__ Kh,
                            uint16_t* __restrict__ Vt) {
    __shared__ float red[4];
    int blk = blockIdx.x; int b = blk >> 10, i = blk & 1023;
    int tid = threadIdx.x, lane = tid & 63, w = tid >> 6;
    const float* row = qkv + (size_t)blk * 2048;
    int c0 = tid * 2;
    int d0 = c0 & 63, head = c0 >> 6;
    int j0 = d0 & 31, j1 = (d0 + 1) & 31;
    const float LN1E4_64 = 0.14391156831212787f;   // ln(10000)/64
    float fi = (float)i;
    float ang0 = fi * __expf(-(float)(4 * j0 + 1) * LN1E4_64);
    float ang1 = fi * __expf(-(float)(4 * j1 + 1) * LN1E4_64);
    float c_0 = cosf(ang0), s_0 = sinf(ang0);
    float c_1 = cosf(ang1), s_1 = sinf(ang1);
    float g0 = lnw[c0], g1 = lnw[c0 + 1];
    for (int which = 0; which < 3; which++) {        // q(e=0), q(e=1), k
        int off = which * 512;
        float u0 = row[off + c0], u1 = row[off + c0 + 1];
        float ss = u0 * u0 + u1 * u1;
        for (int m = 1; m < 64; m <<= 1) ss += __shfl_xor(ss, m);
        __syncthreads();
        if (lane == 0) red[w] = ss;
        __syncthreads();
        float tot = red[0] + red[1] + red[2] + red[3];
        float rinv = rsqrtf(tot * (1.0f / 512.0f) + 1e-6f);
        float n0 = u0 * rinv * g0, n1 = u1 * rinv * g1;
        float r0 = n0 * c_0 - n1 * s_0;              // even dim
        float r1 = n1 * c_1 + n0 * s_1;              // odd dim (different angle!)
        uint32_t pk = (uint32_t)f2bf(r0) | ((uint32_t)f2bf(r1) << 16);
        if (which < 2) {
            uint16_t* dstp = Qh + ((size_t)((b * 2 + which) * 8 + head) * 1024 + i) * 64 + d0;
            *(uint32_t*)dstp = pk;
        } else {
            uint16_t* dstp = Kh + ((size_t)(b * 8 + head) * 1024 + i) * 64 + d0;
            *(uint32_t*)dstp = pk;
        }
    }
    {   // v: no norm/rope; store transposed [d][swz(kv)] so PV A-frags are 16B-contiguous.
        // within each 64-block: off(t,g,j)=t*16+g*4+j  ->  g*16+t*4+j
        int swi = (i & ~63) | (((i >> 2) & 3) << 4) | (((i >> 4) & 3) << 2) | (i & 3);
        float u0 = row[1536 + c0], u1 = row[1536 + c0 + 1];
        Vt[((size_t)(b * 8 + head) * 64 + d0) * 1024 + swi]     = f2bf(u0);
        Vt[((size_t)(b * 8 + head) * 64 + d0 + 1) * 1024 + swi] = f2bf(u1);
    }
}

// 8. causal flash attention, split-KV x2. block=(qb desc, inst, split), 4 waves x 16 q rows.
//    Swapped QK^T => P lane-local; PV via 16x16x16 MFMA from swizzled V (16B loads).
//    Writes unnormalized partials (o bf16, m/ls f32); k_combine merges.
__global__ __launch_bounds__(256, 4) void k_attn(const uint16_t* __restrict__ Qh,
                                                 const uint16_t* __restrict__ Kh,
                                                 const uint16_t* __restrict__ Vt,
                                                 uint16_t* __restrict__ po,
                                                 float2* __restrict__ pml) {
    int blk = blockIdx.x;
    int qb = 15 - (blk >> 6);          // big blocks first
    int inst = (blk >> 1) & 31;        // ((b*2+e)*8+h)
    int s = blk & 1;
    int h = inst & 7, b = inst >> 4;
    int tid = threadIdx.x, lane = tid & 63, w = tid >> 6;
    int qw = qb * 64 + w * 16;
    const uint16_t* Qb = Qh + ((size_t)inst * 1024 + qw) * 64;
    const uint16_t* Kb = Kh + (size_t)(b * 8 + h) * 1024 * 64;
    const uint16_t* Vb = Vt + (size_t)(b * 8 + h) * 64 * 1024;
    int cl = lane & 15, gp = lane >> 4;
    bf16x8 qf0 = *(const bf16x8*)&Qb[cl * 64 + gp * 8];
    bf16x8 qf1 = *(const bf16x8*)&Qb[cl * 64 + 32 + gp * 8];
    f32x4 o[4];
#pragma unroll
    for (int dt = 0; dt < 4; dt++)
#pragma unroll
        for (int r = 0; r < 4; r++) o[dt][r] = 0.f;
    float m = -INFINITY, ls = 0.f;
    int qa = qw + cl;

    for (int jt = s * 64; jt <= qw; jt += 128) {
        f32x4 sv[4];
#pragma unroll
        for (int t = 0; t < 4; t++)
#pragma unroll
            for (int r = 0; r < 4; r++) sv[t][r] = 0.f;
#pragma unroll
        for (int t = 0; t < 4; t++) {
            const uint16_t* kr = &Kb[(size_t)(jt + t * 16 + cl) * 64 + gp * 8];
            bf16x8 k0 = *(const bf16x8*)kr;
            bf16x8 k1 = *(const bf16x8*)(kr + 32);
            sv[t] = mfma16(k0, qf0, sv[t]);
            sv[t] = mfma16(k1, qf1, sv[t]);
        }
        // V loads issued early (latency hides under softmax)
        s16x8 vv0[4], vv1[4];
#pragma unroll
        for (int dt = 0; dt < 4; dt++) {
            const uint16_t* vrow = &Vb[(size_t)(dt * 16 + cl) * 1024 + jt + gp * 16];
            vv0[dt] = *(const s16x8*)vrow;           // subtiles t=0 (lo), t=1 (hi)
            vv1[dt] = *(const s16x8*)(vrow + 8);     // subtiles t=2 (lo), t=3 (hi)
        }
        if (jt + 63 > qw) {                          // boundary tile: causal mask
#pragma unroll
            for (int t = 0; t < 4; t++) {
                int kvb = jt + t * 16 + gp * 4;
#pragma unroll
                for (int r = 0; r < 4; r++)
                    sv[t][r] = (kvb + r <= qa) ? sv[t][r] * 0.125f : -INFINITY;
            }
        } else {
#pragma unroll
            for (int t = 0; t < 4; t++)
#pragma unroll
                for (int r = 0; r < 4; r++) sv[t][r] *= 0.125f;
        }
        float tmax = fmaxf(fmaxf(fmaxf(sv[0][0], sv[0][1]), fmaxf(sv[0][2], sv[0][3])),
                           fmaxf(fmaxf(sv[1][0], sv[1][1]), fmaxf(sv[1][2], sv[1][3])));
        tmax = fmaxf(tmax,
               fmaxf(fmaxf(fmaxf(sv[2][0], sv[2][1]), fmaxf(sv[2][2], sv[2][3])),
                     fmaxf(fmaxf(sv[3][0], sv[3][1]), fmaxf(sv[3][2], sv[3][3]))));
        tmax = fmaxf(tmax, __shfl_xor(tmax, 16));
        tmax = fmaxf(tmax, __shfl_xor(tmax, 32));
        float mn = fmaxf(m, tmax);
        float sc = __expf(m - mn);
        m = mn;
        float lsum = 0.f;
#pragma unroll
        for (int t = 0; t < 4; t++)
#pragma unroll
            for (int r = 0; r < 4; r++) {
                float p = __expf(sv[t][r] - mn);
                sv[t][r] = p;
                lsum += p;
            }
        lsum += __shfl_xor(lsum, 16);
        lsum += __shfl_xor(lsum, 32);
        ls = ls * sc + lsum;
#pragma unroll
        for (int dt = 0; dt < 4; dt++) o[dt] *= sc;
        s16x4 pb[4];
#pragma unroll
        for (int t = 0; t < 4; t++)
#pragma unroll
            for (int r = 0; r < 4; r++) pb[t][r] = (short)f2bf(sv[t][r]);
#pragma unroll
        for (int dt = 0; dt < 4; dt++) {
            s16x4 a0 = __builtin_shufflevector(vv0[dt], vv0[dt], 0, 1, 2, 3);
            s16x4 a1 = __builtin_shufflevector(vv0[dt], vv0[dt], 4, 5, 6, 7);
            s16x4 a2 = __builtin_shufflevector(vv1[dt], vv1[dt], 0, 1, 2, 3);
            s16x4 a3 = __builtin_shufflevector(vv1[dt], vv1[dt], 4, 5, 6, 7);
            o[dt] = mfma_k16(a0, pb[0], o[dt]);
            o[dt] = mfma_k16(a1, pb[1], o[dt]);
            o[dt] = mfma_k16(a2, pb[2], o[dt]);
            o[dt] = mfma_k16(a3, pb[3], o[dt]);
        }
    }
    // write partials (unnormalized)
    size_t pbase = ((size_t)(inst * 1024 + qw + cl) * 2 + s);
    uint16_t* pr = po + pbase * 64;
#pragma unroll
    for (int dt = 0; dt < 4; dt++) {
        uint16_t pk[4];
#pragma unroll
        for (int r = 0; r < 4; r++) pk[r] = f2bf(o[dt][r]);
        *(uint2*)&pr[dt * 16 + gp * 4] = *(const uint2*)pk;
    }
    if (gp == 0) pml[pbase] = make_float2(m, ls);
}

// 8b. merge 2 KV-split partials -> ybf
__global__ void k_combine(const uint16_t* __restrict__ po, const float2* __restrict__ pml,
                          uint16_t* __restrict__ ybf) {
    int gid = blockIdx.x * blockDim.x + threadIdx.x;   // 1M threads
    int dp = gid & 31, row = (gid >> 5) & 1023, inst = gid >> 15;
    size_t p0 = ((size_t)(inst * 1024 + row)) * 2;
    float2 ml0 = pml[p0], ml1 = pml[p0 + 1];
    float M = fmaxf(ml0.x, ml1.x);
    float w0 = __expf(ml0.x - M), w1 = __expf(ml1.x - M);
    float inv = 1.f / (w0 * ml0.y + w1 * ml1.y);
    const uint32_t* po32 = (const uint32_t*)po;
    uint32_t a = po32[p0 * 32 + dp], c = po32[(p0 + 1) * 32 + dp];
    float r0 = (w0 * bf2f(a & 0xffff) + w1 * bf2f(c & 0xffff)) * inv;
    float r1 = (w0 * bf2f(a >> 16)    + w1 * bf2f(c >> 16))    * inv;
    uint32_t pk = (uint32_t)f2bf(r0) | ((uint32_t)f2bf(r1) << 16);
    int h = inst & 7, be = inst >> 3;
    *(uint32_t*)&ybf[(size_t)(be * 1024 + row) * 512 + h * 64 + dp * 2] = pk;
}

// 9. epilogue: out = x (+ gated expert mix on selected rows)
__global__ void k_epilogue(const float* __restrict__ x, const int* __restrict__ posmap,
                           const float* __restrict__ yproj, const float* __restrict__ gate,
                           const float* __restrict__ wsel, float* __restrict__ out) {
    int row = blockIdx.x;                 // 4096
    int b = row >> 11;
    int tid = threadIdx.x;                // 128
    const float4* xr = (const float4*)(x + (size_t)row * 512);
    float4* orow = (float4*)(out + (size_t)row * 512);
    float4 v = xr[tid];
    int pos = posmap[row];
    if (pos >= 0) {
        int bk = b * 1024 + pos;
        float wv = wsel[bk], g0 = gate[bk * 2], g1 = gate[bk * 2 + 1];
        const float4* y0 = (const float4*)(yproj + ((size_t)(b * 2) * 1024 + pos) * 512);
        const float4* y1 = (const float4*)(yproj + ((size_t)(b * 2 + 1) * 1024 + pos) * 512);
        float4 a = y0[tid], c = y1[tid];
        v.x += wv * (g0 * a.x + g1 * c.x);
        v.y += wv * (g0 * a.y + g1 * c.y);
        v.z += wv * (g0 * a.z + g1 * c.z);
        v.w += wv * (g0 * a.w + g1 * c.w);
    }
    orow[tid] = v;
}

// 10. BCE loss from precomputed predictor logits. single block.
__global__ void k_loss(const float* __restrict__ pl, const int* __restrict__ mask,
                       float* __restrict__ outloss) {
    __shared__ float red[16];
    int tid = threadIdx.x;                // 1024
    float s = 0.f;
#pragma unroll
    for (int j = 0; j < 4; j++) {
        int i = tid * 4 + j;
        float p = pl[i];
        float tgt = (float)mask[i];
        s += fmaxf(p, 0.f) - p * tgt + log1pf(__expf(-fabsf(p)));
    }
    for (int mm = 1; mm < 64; mm <<= 1) s += __shfl_xor(s, mm);
    int lane = tid & 63, w = tid >> 6;
    if (lane == 0) red[w] = s;
    __syncthreads();
    if (tid == 0) {
        float t = 0.f;
        for (int q = 0; q < 16; q++) t += red[q];
        outloss[0] = t * (1.0f / 4096.0f);
    }
}

// ---------------------------------------------------------------------------
extern "C" void kernel_launch(void* const* d_in, const int* in_sizes, int n_in,
                              void* d_out, int out_size, void* d_ws, size_t ws_size,
                              hipStream_t stream) {
    const float* x        = (const float*)d_in[0];
    const float* W_router = (const float*)d_in[1];
    const float* W_q      = (const float*)d_in[2];
    const float* W_kv     = (const float*)d_in[3];
    const float* W_proj   = (const float*)d_in[4];
    const float* ln_w     = (const float*)d_in[5];
    const float* W_gate   = (const float*)d_in[6];
    const float* W_pred   = (const float*)d_in[7];

    char* ws = (char*)d_ws;
    float*    logits = (float*)   (ws + OFF_LOGITS);
    float*    pl     = (float*)   (ws + OFF_PL);
    int*      mask   = (int*)     (ws + OFF_MASK);
    int*      posmap = (int*)     (ws + OFF_POSMAP);
    int*      idx    = (int*)     (ws + OFF_IDX);
    float*    wsel   = (float*)   (ws + OFF_WSEL);
    float*    gate   = (float*)   (ws + OFF_GATE);
    uint16_t* selbf  = (uint16_t*)(ws + OFF_SELBF);
    uint16_t* Wqkvt  = (uint16_t*)(ws + OFF_WQKVT);
    uint16_t* Wprojt = (uint16_t*)(ws + OFF_WPROJT);
    float*    qkvraw = (float*)   (ws + OFF_QKVRAW);
    uint16_t* po     = (uint16_t*)(ws + OFF_PO);
    float2*   pml    = (float2*)  (ws + OFF_PML);
    uint16_t* Qh     = (uint16_t*)(ws + OFF_QH);
    uint16_t* Kh     = (uint16_t*)(ws + OFF_KH);
    uint16_t* Vt     = (uint16_t*)(ws + OFF_VT);
    uint16_t* ybf    = (uint16_t*)(ws + OFF_YBF);
    float*    yproj  = (float*)   (ws + OFF_YPROJ);
    float*    out    = (float*)d_out;

    k_castw      <<<320, 256, 0, stream>>>(W_q, W_kv, W_proj, Wqkvt, Wprojt);
    k_router     <<<1024, 256, 0, stream>>>(x, W_router, W_pred, logits, pl);
    k_rank       <<<1024, 256, 0, stream>>>(logits, mask);
    k_select     <<<2, 1024, 0, stream>>>(logits, mask, idx, wsel, posmap);
    k_gather_gate<<<2048, 256, 0, stream>>>(x, idx, W_gate, selbf, gate);
    k_gemm       <<<dim3(16, 16), 256, 0, stream>>>(selbf, Wqkvt, qkvraw, 2048, 2048, 512);
    k_norm_rope  <<<2048, 256, 0, stream>>>(qkvraw, ln_w, Qh, Kh, Vt);
    k_attn       <<<1024, 256, 0, stream>>>(Qh, Kh, Vt, po, pml);
    k_combine    <<<4096, 256, 0, stream>>>(po, pml, ybf);
    k_gemm       <<<dim3(32, 4), 256, 0, stream>>>(ybf, Wprojt, yproj, 4096, 512, 512);
    k_epilogue   <<<4096, 128, 0, stream>>>(x, posmap, yproj, gate, wsel, out);
    k_loss       <<<1, 1024, 0, stream>>>(pl, mask, out + 2097152);
}

// Round 5
// 112.651 us; speedup vs baseline: 1.4360x; 1.0684x over previous
//
#include <hip/hip_runtime.h>
#include <cstdint>

// ---------------------------------------------------------------------------
// MoDBlock: B=2, T=2048, C=512, E=2, NH=8, hs=64, k=1024 (hardcoded).
// Output: out [B,T,C] f32 (2097152) + loss (1).
// ---------------------------------------------------------------------------

#define DI __device__ __forceinline__

typedef __bf16 bf16x8 __attribute__((ext_vector_type(8)));
typedef float  f32x4  __attribute__((ext_vector_type(4)));
typedef short  s16x4  __attribute__((ext_vector_type(4)));
typedef short  s16x8  __attribute__((ext_vector_type(8)));

DI uint16_t f2bf(float f) {
    union { float f; uint32_t u; } v; v.f = f;
    uint32_t u = v.u;
    uint32_t r = (u + 0x7FFFu + ((u >> 16) & 1u)) >> 16;   // RNE; finite inputs only
    return (uint16_t)r;
}
DI float bf2f(uint32_t lo16) {
    union { uint32_t u; float f; } v; v.u = lo16 << 16; return v.f;
}

DI f32x4 mfma16(bf16x8 a, bf16x8 b, f32x4 c) {
    return __builtin_amdgcn_mfma_f32_16x16x32_bf16(a, b, c, 0, 0, 0);
}
DI f32x4 mfma_k16(s16x4 a, s16x4 b, f32x4 c) {
    return __builtin_amdgcn_mfma_f32_16x16x16bf16_1k(a, b, c, 0, 0, 0);
}

// ---- workspace layout (bytes) ----
constexpr size_t OFF_LOGITS = 0;                                // 4096 f32
constexpr size_t OFF_PL     = OFF_LOGITS + 4096 * 4;            // 4096 f32
constexpr size_t OFF_MASK   = OFF_PL     + 4096 * 4;            // 4096 int
constexpr size_t OFF_POSMAP = OFF_MASK   + 4096 * 4;            // 4096 int
constexpr size_t OFF_IDX    = OFF_POSMAP + 4096 * 4;            // 2048 int
constexpr size_t OFF_WSEL   = OFF_IDX    + 2048 * 4;            // 2048 f32
constexpr size_t OFF_GATE   = OFF_WSEL   + 2048 * 4;            // 2048*2 f32
constexpr size_t OFF_SELBF  = OFF_GATE   + 4096 * 4;            // 2048*512 bf16
constexpr size_t OFF_WQKVT  = OFF_SELBF  + 2048 * 512 * 2;      // [2048][512] bf16
constexpr size_t OFF_WPROJT = OFF_WQKVT  + 2048 * 512 * 2;      // [512][512] bf16
constexpr size_t OFF_QKVRAW = OFF_WPROJT + 512 * 512 * 2;       // 2048*2048 f32 (16.78MB)
// attention partials: po ALIASES qkvraw exactly (dead after norm_rope/vt)
constexpr size_t OFF_PO     = OFF_QKVRAW;                       // 32*1024*4*64 bf16 = 16.78MB
constexpr size_t OFF_QH     = OFF_QKVRAW + (size_t)2048 * 2048 * 4; // [B,E,NH,k,64] bf16
constexpr size_t OFF_KH     = OFF_QH     + (size_t)2097152 * 2;     // [B,NH,k,64] bf16 (pre-scaled 1/8)
constexpr size_t OFF_VT     = OFF_KH     + (size_t)1048576 * 2;     // [B,NH,64,k] bf16 (kv-swizzled)
constexpr size_t OFF_YBF    = OFF_VT     + (size_t)1048576 * 2;     // [B,E,k,512] bf16
constexpr size_t OFF_PML    = OFF_YBF    + (size_t)4096 * 512 * 2;  // 32*1024*4 float2 = 1MB
constexpr int NSPLIT = 4;

// ---------------------------------------------------------------------------
// 1. router logits (f64 accum, top-k boundary safety) + predictor logits.
__global__ void k_router(const float* __restrict__ x, const float* __restrict__ wr,
                         const float* __restrict__ wp,
                         float* __restrict__ logits, float* __restrict__ pl) {
    int wid  = (blockIdx.x * blockDim.x + threadIdx.x) >> 6;
    int lane = threadIdx.x & 63;
    if (wid >= 4096) return;
    const float* xr = x + (size_t)wid * 512;
    double s = 0.0; float sp = 0.f;
#pragma unroll
    for (int j = 0; j < 8; j++) {
        int c = lane + 64 * j;
        float xv = xr[c];
        s  += (double)xv * (double)wr[c];
        sp += xv * wp[c];
    }
    for (int m = 1; m < 64; m <<= 1) { s += __shfl_xor(s, m); sp += __shfl_xor(sp, m); }
    if (lane == 0) { logits[wid] = (float)s; pl[wid] = sp; }
}

// 2. rank: count of strictly-greater (or equal with smaller index) -> mask
__global__ void k_rank(const float* __restrict__ logits, int* __restrict__ mask) {
    int wid  = (blockIdx.x * blockDim.x + threadIdx.x) >> 6;
    int lane = threadIdx.x & 63;
    if (wid >= 4096) return;
    int b = wid >> 11, t = wid & 2047;
    const float* lb = logits + b * 2048;
    float v = lb[t];
    int cnt = 0;
    for (int j = 0; j < 32; j++) {
        int tp = lane + 64 * j;
        float lv = lb[tp];
        bool pred = (lv > v) || (lv == v && tp < t);
        cnt += __popcll(__ballot(pred));
    }
    if (lane == 0) mask[wid] = (cnt < 1024) ? 1 : 0;
}

// 3. wave-scan selection: idx (temporal order), wsel, posmap. 1 block/batch.
__global__ void k_select(const float* __restrict__ logits, const int* __restrict__ mask,
                         int* __restrict__ idx, float* __restrict__ wsel,
                         int* __restrict__ posmap) {
    __shared__ int wsum[16], woff[16];
    int b = blockIdx.x, tid = threadIdx.x, lane = tid & 63, w = tid >> 6;
    int t0 = tid * 2, t1 = tid * 2 + 1;
    int m0 = mask[b * 2048 + t0], m1 = mask[b * 2048 + t1];
    int s = m0 + m1;
    int sc = s;
    for (int off = 1; off < 64; off <<= 1) {
        int v = __shfl_up(sc, off);
        if (lane >= off) sc += v;
    }
    if (lane == 63) wsum[w] = sc;
    __syncthreads();
    if (tid < 16) {
        int acc = 0;
        for (int j = 0; j < tid; j++) acc += wsum[j];
        woff[tid] = acc;
    }
    __syncthreads();
    int excl = woff[w] + sc - s;
    int p0 = excl, p1 = excl + m0;
    if (m0) {
        idx[b * 1024 + p0] = t0;
        float v = logits[b * 2048 + t0];
        wsel[b * 1024 + p0] = 1.f / (1.f + __expf(-v));
    }
    posmap[b * 2048 + t0] = m0 ? p0 : -1;
    if (m1) {
        idx[b * 1024 + p1] = t1;
        float v = logits[b * 2048 + t1];
        wsel[b * 1024 + p1] = 1.f / (1.f + __expf(-v));
    }
    posmap[b * 2048 + t1] = m1 ? p1 : -1;
}

// 4. weight transpose+cast via LDS 64x64 tile (blocks 0..319) + x->out copy (320..2367)
__global__ __launch_bounds__(256) void k_castw(const float* __restrict__ Wq,
                                               const float* __restrict__ Wkv,
                                               const float* __restrict__ Wp,
                                               uint16_t* __restrict__ Wqkvt,
                                               uint16_t* __restrict__ Wprojt,
                                               const float4* __restrict__ xsrc,
                                               float4* __restrict__ outdst) {
    __shared__ float tile[64][65];
    int blk = blockIdx.x, tid = threadIdx.x;
    if (blk >= 320) {                  // copy x -> out (524288 float4)
        int j = (blk - 320) * 256 + tid;
        outdst[j] = xsrc[j];
        return;
    }
    const float* src; uint16_t* dst; int n0, c0, ldn;
    if (blk < 256) {                   // qkv: dest [2048][512]
        int tn = blk & 31, tc = blk >> 5;
        n0 = tn * 64; c0 = tc * 64; ldn = 1024;
        if (n0 < 1024) { src = Wq; } else { src = Wkv; n0 -= 1024; }
        dst = Wqkvt + (size_t)(tn * 64) * 512 + c0;
    } else {                           // proj: dest [512][512]
        int j = blk - 256; int tn = j & 7, tc = j >> 3;
        n0 = tn * 64; c0 = tc * 64; ldn = 512;
        src = Wp; dst = Wprojt + (size_t)n0 * 512 + c0;
    }
    int nl = tid & 63, cb = tid >> 6;
#pragma unroll
    for (int p = 0; p < 16; p++) {
        int cl_ = p * 4 + cb;
        tile[cl_][nl] = src[(size_t)(c0 + cl_) * ldn + n0 + nl];
    }
    __syncthreads();
    int cp = tid & 31, nb = tid >> 5;
#pragma unroll
    for (int p = 0; p < 8; p++) {
        int nl2 = p * 8 + nb;
        uint32_t pk = (uint32_t)f2bf(tile[cp * 2][nl2]) |
                      ((uint32_t)f2bf(tile[cp * 2 + 1][nl2]) << 16);
        *(uint32_t*)&dst[(size_t)nl2 * 512 + cp * 2] = pk;
    }
}

// 5. gather selected rows -> bf16, gate = softmax(sel @ W_gate)
__global__ void k_gather_gate(const float* __restrict__ x, const int* __restrict__ idx,
                              const float* __restrict__ Wg,
                              uint16_t* __restrict__ selbf, float* __restrict__ gate) {
    __shared__ float red0[4], red1[4];
    int blk = blockIdx.x; int b = blk >> 10;
    int tid = threadIdx.x, lane = tid & 63, w = tid >> 6;
    int t = idx[blk];
    const float* xr = x + ((size_t)b * 2048 + t) * 512;
    int c = tid * 2;
    float v0 = xr[c], v1 = xr[c + 1];
    uint32_t pk = (uint32_t)f2bf(v0) | ((uint32_t)f2bf(v1) << 16);
    ((uint32_t*)(selbf + (size_t)blk * 512))[tid] = pk;
    float g0 = v0 * Wg[c * 2]     + v1 * Wg[(c + 1) * 2];
    float g1 = v0 * Wg[c * 2 + 1] + v1 * Wg[(c + 1) * 2 + 1];
    for (int m = 1; m < 64; m <<= 1) { g0 += __shfl_xor(g0, m); g1 += __shfl_xor(g1, m); }
    if (lane == 0) { red0[w] = g0; red1[w] = g1; }
    __syncthreads();
    if (tid == 0) {
        float a = red0[0] + red0[1] + red0[2] + red0[3];
        float bq = red1[0] + red1[1] + red1[2] + red1[3];
        float mx = fmaxf(a, bq);
        float ea = __expf(a - mx), eb = __expf(bq - mx), s = ea + eb;
        gate[blk * 2] = ea / s; gate[blk * 2 + 1] = eb / s;
    }
}

// 6. bf16 MFMA GEMM: C[M,N] f32 = A[M,K]bf16 @ Bt[N,K]^T. 128x128 tile, BK=32.
__global__ __launch_bounds__(256) void k_gemm(const uint16_t* __restrict__ A,
                                              const uint16_t* __restrict__ Bt,
                                              float* __restrict__ Cc,
                                              int M, int N, int Kd) {
    __shared__ uint16_t As[128 * 40], Bs[128 * 40];
    int tid = threadIdx.x, lane = tid & 63, w = tid >> 6;
    int m0 = blockIdx.x * 128, n0 = blockIdx.y * 128;
    int wr = (w >> 1) * 64, wc = (w & 1) * 64;
    f32x4 acc[4][4];
#pragma unroll
    for (int mt = 0; mt < 4; mt++)
#pragma unroll
        for (int nt = 0; nt < 4; nt++)
#pragma unroll
            for (int r = 0; r < 4; r++) acc[mt][nt][r] = 0.f;
    int arow = tid >> 2, akg = tid & 3;
    int K8 = Kd >> 3;
    const bf16x8* A8 = (const bf16x8*)A;
    const bf16x8* B8 = (const bf16x8*)Bt;
    for (int ks = 0; ks < Kd; ks += 32) {
        __syncthreads();
        int kc = (ks >> 3) + akg;
        bf16x8 va0 = A8[(size_t)(m0 + arow) * K8 + kc];
        bf16x8 va1 = A8[(size_t)(m0 + arow + 64) * K8 + kc];
        bf16x8 vb0 = B8[(size_t)(n0 + arow) * K8 + kc];
        bf16x8 vb1 = B8[(size_t)(n0 + arow + 64) * K8 + kc];
        *(bf16x8*)&As[arow * 40 + akg * 8] = va0;
        *(bf16x8*)&As[(arow + 64) * 40 + akg * 8] = va1;
        *(bf16x8*)&Bs[arow * 40 + akg * 8] = vb0;
        *(bf16x8*)&Bs[(arow + 64) * 40 + akg * 8] = vb1;
        __syncthreads();
        bf16x8 af[4], bfr[4];
#pragma unroll
        for (int t = 0; t < 4; t++) {
            af[t]  = *(const bf16x8*)&As[(wr + t * 16 + (lane & 15)) * 40 + (lane >> 4) * 8];
            bfr[t] = *(const bf16x8*)&Bs[(wc + t * 16 + (lane & 15)) * 40 + (lane >> 4) * 8];
        }
#pragma unroll
        for (int mt = 0; mt < 4; mt++)
#pragma unroll
            for (int nt = 0; nt < 4; nt++)
                acc[mt][nt] = mfma16(af[mt], bfr[nt], acc[mt][nt]);
    }
    int r0 = (lane >> 4) * 4, cl = lane & 15;
#pragma unroll
    for (int mt = 0; mt < 4; mt++)
#pragma unroll
        for (int nt = 0; nt < 4; nt++)
#pragma unroll
            for (int r = 0; r < 4; r++) {
                int row = m0 + wr + mt * 16 + r0 + r;
                int col = n0 + wc + nt * 16 + cl;
                Cc[(size_t)row * N + col] = acc[mt][nt][r];
            }
}

// 7. RMSNorm + RoPE -> head-layout bf16 Q and K (K pre-scaled by 1/8)
__global__ void k_norm_rope(const float* __restrict__ qkv, const float* __restrict__ lnw,
                            uint16_t* __restrict__ Qh, uint16_t* __restrict__ Kh) {
    __shared__ float red[4];
    int blk = blockIdx.x; int b = blk >> 10, i = blk & 1023;
    int tid = threadIdx.x, lane = tid & 63, w = tid >> 6;
    const float* row = qkv + (size_t)blk * 2048;
    int c0 = tid * 2;
    int d0 = c0 & 63, head = c0 >> 6;
    int j0 = d0 & 31, j1 = (d0 + 1) & 31;
    const float LN1E4_64 = 0.14391156831212787f;   // ln(10000)/64
    float fi = (float)i;
    float ang0 = fi * __expf(-(float)(4 * j0 + 1) * LN1E4_64);
    float ang1 = fi * __expf(-(float)(4 * j1 + 1) * LN1E4_64);
    float c_0 = cosf(ang0), s_0 = sinf(ang0);
    float c_1 = cosf(ang1), s_1 = sinf(ang1);
    float g0 = lnw[c0], g1 = lnw[c0 + 1];
    for (int which = 0; which < 3; which++) {        // q(e=0), q(e=1), k
        int off = which * 512;
        float u0 = row[off + c0], u1 = row[off + c0 + 1];
        float ss = u0 * u0 + u1 * u1;
        for (int m = 1; m < 64; m <<= 1) ss += __shfl_xor(ss, m);
        __syncthreads();
        if (lane == 0) red[w] = ss;
        __syncthreads();
        float tot = red[0] + red[1] + red[2] + red[3];
        float rinv = rsqrtf(tot * (1.0f / 512.0f) + 1e-6f);
        float n0 = u0 * rinv * g0, n1 = u1 * rinv * g1;
        float r0 = n0 * c_0 - n1 * s_0;              // even dim
        float r1 = n1 * c_1 + n0 * s_1;              // odd dim (different angle!)
        if (which < 2) {
            uint32_t pk = (uint32_t)f2bf(r0) | ((uint32_t)f2bf(r1) << 16);
            uint16_t* dstp = Qh + ((size_t)((b * 2 + which) * 8 + head) * 1024 + i) * 64 + d0;
            *(uint32_t*)dstp = pk;
        } else {                                     // K: fold 1/sqrt(hs)
            uint32_t pk = (uint32_t)f2bf(r0 * 0.125f) | ((uint32_t)f2bf(r1 * 0.125f) << 16);
            uint16_t* dstp = Kh + ((size_t)(b * 8 + head) * 1024 + i) * 64 + d0;
            *(uint32_t*)dstp = pk;
        }
    }
}

// 7b. V transpose: qkvraw cols 1536.. -> Vt[bh][64][swz(1024)] bf16, coalesced both sides
__global__ __launch_bounds__(256) void k_vt(const float* __restrict__ qkv,
                                            uint16_t* __restrict__ Vt) {
    __shared__ float tile[64][65];
    int bh = blockIdx.x >> 4, kt = blockIdx.x & 15;  // 16 bh x 16 kv-tiles
    int b = bh >> 3, h = bh & 7;
    int tid = threadIdx.x;
    int r = tid >> 2, cg = tid & 3;                  // load phase: row r, col group cg
    const float* srow = qkv + ((size_t)(b * 1024 + kt * 64 + r)) * 2048 + 1536 + h * 64 + cg * 16;
#pragma unroll
    for (int p = 0; p < 4; p++) {
        float4 v = *(const float4*)(srow + p * 4);
        tile[r][cg * 16 + p * 4 + 0] = v.x;
        tile[r][cg * 16 + p * 4 + 1] = v.y;
        tile[r][cg * 16 + p * 4 + 2] = v.z;
        tile[r][cg * 16 + p * 4 + 3] = v.w;
    }
    __syncthreads();
    int d = tid >> 2, kg = tid & 3;                  // store phase: dim d, kv group
    int t4 = kg;                                     // i_local = t4*16 + g*4 + j
    uint16_t* drow = Vt + ((size_t)(bh * 64 + d)) * 1024 + kt * 64;
#pragma unroll
    for (int g = 0; g < 4; g++) {
        uint16_t pk[4];
#pragma unroll
        for (int j = 0; j < 4; j++) pk[j] = f2bf(tile[t4 * 16 + g * 4 + j][d]);
        *(uint2*)&drow[g * 16 + t4 * 4] = *(const uint2*)pk;   // swz: i' = g*16 + t*4 + j
    }
}

// 8. causal flash attention, split-KV x4. block=(qb desc, inst, split), 4 waves x 16 q rows.
//    Swapped QK^T (K pre-scaled) => P lane-local; PV via 16x16x16 MFMA from swizzled V.
__global__ __launch_bounds__(256, 4) void k_attn(const uint16_t* __restrict__ Qh,
                                                 const uint16_t* __restrict__ Kh,
                                                 const uint16_t* __restrict__ Vt,
                                                 uint16_t* __restrict__ po,
                                                 float2* __restrict__ pml) {
    int blk = blockIdx.x;
    int qb = 15 - (blk >> 7);          // big blocks first
    int rest = blk & 127;
    int inst = rest >> 2;              // ((b*2+e)*8+h)
    int s = rest & 3;
    int h = inst & 7, b = inst >> 4;
    int tid = threadIdx.x, lane = tid & 63, w = tid >> 6;
    int qw = qb * 64 + w * 16;
    const uint16_t* Qb = Qh + ((size_t)inst * 1024 + qw) * 64;
    const uint16_t* Kb = Kh + (size_t)(b * 8 + h) * 1024 * 64;
    const uint16_t* Vb = Vt + (size_t)(b * 8 + h) * 64 * 1024;
    int cl = lane & 15, gp = lane >> 4;
    bf16x8 qf0 = *(const bf16x8*)&Qb[cl * 64 + gp * 8];
    bf16x8 qf1 = *(const bf16x8*)&Qb[cl * 64 + 32 + gp * 8];
    f32x4 o[4];
#pragma unroll
    for (int dt = 0; dt < 4; dt++)
#pragma unroll
        for (int r = 0; r < 4; r++) o[dt][r] = 0.f;
    float m = -INFINITY, ls = 0.f;
    int qa = qw + cl;

    for (int jt = s * 64; jt <= qw; jt += NSPLIT * 64) {
        f32x4 sv[4];
#pragma unroll
        for (int t = 0; t < 4; t++)
#pragma unroll
            for (int r = 0; r < 4; r++) sv[t][r] = 0.f;
#pragma unroll
        for (int t = 0; t < 4; t++) {
            const uint16_t* kr = &Kb[(size_t)(jt + t * 16 + cl) * 64 + gp * 8];
            bf16x8 k0 = *(const bf16x8*)kr;
            bf16x8 k1 = *(const bf16x8*)(kr + 32);
            sv[t] = mfma16(k0, qf0, sv[t]);
            sv[t] = mfma16(k1, qf1, sv[t]);
        }
        // V loads issued early (latency hides under softmax)
        s16x8 vv0[4], vv1[4];
#pragma unroll
        for (int dt = 0; dt < 4; dt++) {
            const uint16_t* vrow = &Vb[(size_t)(dt * 16 + cl) * 1024 + jt + gp * 16];
            vv0[dt] = *(const s16x8*)vrow;
            vv1[dt] = *(const s16x8*)(vrow + 8);
        }
        if (jt + 63 > qw) {                          // boundary tile: causal mask
#pragma unroll
            for (int t = 0; t < 4; t++) {
                int kvb = jt + t * 16 + gp * 4;
#pragma unroll
                for (int r = 0; r < 4; r++)
                    sv[t][r] = (kvb + r <= qa) ? sv[t][r] : -INFINITY;
            }
        }
        float tmax = fmaxf(fmaxf(fmaxf(sv[0][0], sv[0][1]), fmaxf(sv[0][2], sv[0][3])),
                           fmaxf(fmaxf(sv[1][0], sv[1][1]), fmaxf(sv[1][2], sv[1][3])));
        tmax = fmaxf(tmax,
               fmaxf(fmaxf(fmaxf(sv[2][0], sv[2][1]), fmaxf(sv[2][2], sv[2][3])),
                     fmaxf(fmaxf(sv[3][0], sv[3][1]), fmaxf(sv[3][2], sv[3][3]))));
        tmax = fmaxf(tmax, __shfl_xor(tmax, 16));
        tmax = fmaxf(tmax, __shfl_xor(tmax, 32));
        float mn = fmaxf(m, tmax);
        float sc = __expf(m - mn);
        m = mn;
        float lsum = 0.f;
#pragma unroll
        for (int t = 0; t < 4; t++)
#pragma unroll
            for (int r = 0; r < 4; r++) {
                float p = __expf(sv[t][r] - mn);
                sv[t][r] = p;
                lsum += p;
            }
        lsum += __shfl_xor(lsum, 16);
        lsum += __shfl_xor(lsum, 32);
        ls = ls * sc + lsum;
#pragma unroll
        for (int dt = 0; dt < 4; dt++) o[dt] *= sc;
        s16x4 pb[4];
#pragma unroll
        for (int t = 0; t < 4; t++)
#pragma unroll
            for (int r = 0; r < 4; r++) pb[t][r] = (short)f2bf(sv[t][r]);
#pragma unroll
        for (int dt = 0; dt < 4; dt++) {
            s16x4 a0 = __builtin_shufflevector(vv0[dt], vv0[dt], 0, 1, 2, 3);
            s16x4 a1 = __builtin_shufflevector(vv0[dt], vv0[dt], 4, 5, 6, 7);
            s16x4 a2 = __builtin_shufflevector(vv1[dt], vv1[dt], 0, 1, 2, 3);
            s16x4 a3 = __builtin_shufflevector(vv1[dt], vv1[dt], 4, 5, 6, 7);
            o[dt] = mfma_k16(a0, pb[0], o[dt]);
            o[dt] = mfma_k16(a1, pb[1], o[dt]);
            o[dt] = mfma_k16(a2, pb[2], o[dt]);
            o[dt] = mfma_k16(a3, pb[3], o[dt]);
        }
    }
    // write partials (unnormalized)
    size_t pbase = ((size_t)(inst * 1024 + qw + cl) * NSPLIT + s);
    uint16_t* pr = po + pbase * 64;
#pragma unroll
    for (int dt = 0; dt < 4; dt++) {
        uint16_t pk[4];
#pragma unroll
        for (int r = 0; r < 4; r++) pk[r] = f2bf(o[dt][r]);
        *(uint2*)&pr[dt * 16 + gp * 4] = *(const uint2*)pk;
    }
    if (gp == 0) pml[pbase] = make_float2(m, ls);
}

// 8b. merge KV-split partials -> ybf
__global__ void k_combine(const uint16_t* __restrict__ po, const float2* __restrict__ pml,
                          uint16_t* __restrict__ ybf) {
    int gid = blockIdx.x * blockDim.x + threadIdx.x;   // 1M threads
    int dp = gid & 31, row = (gid >> 5) & 1023, inst = gid >> 15;
    size_t p0 = ((size_t)(inst * 1024 + row)) * NSPLIT;
    float2 ml[NSPLIT];
#pragma unroll
    for (int s = 0; s < NSPLIT; s++) ml[s] = pml[p0 + s];
    float M = fmaxf(fmaxf(ml[0].x, ml[1].x), fmaxf(ml[2].x, ml[3].x));
    float wq[NSPLIT]; float den = 0.f;
#pragma unroll
    for (int s = 0; s < NSPLIT; s++) { wq[s] = __expf(ml[s].x - M); den += wq[s] * ml[s].y; }
    float inv = 1.f / den;
    const uint32_t* po32 = (const uint32_t*)po;
    float r0 = 0.f, r1 = 0.f;
#pragma unroll
    for (int s = 0; s < NSPLIT; s++) {
        uint32_t a = po32[(p0 + s) * 32 + dp];
        r0 += wq[s] * bf2f(a & 0xffff);
        r1 += wq[s] * bf2f(a >> 16);
    }
    uint32_t pk = (uint32_t)f2bf(r0 * inv) | ((uint32_t)f2bf(r1 * inv) << 16);
    int h = inst & 7, be = inst >> 3;
    *(uint32_t*)&ybf[(size_t)(be * 1024 + row) * 512 + h * 64 + dp * 2] = pk;
}

// 9. fused proj-GEMM + gated combine + scatter-add into out.
__global__ __launch_bounds__(256) void k_projc(const uint16_t* __restrict__ ybf,
                                               const uint16_t* __restrict__ Wprojt,
                                               const int* __restrict__ idx,
                                               const float* __restrict__ wsel,
                                               const float* __restrict__ gate,
                                               float* __restrict__ out) {
    __shared__ uint16_t As0[64 * 40], As1[64 * 40], Bs[64 * 40];
    int pid = blockIdx.x;              // 32: b = pid>>4, pt = pid&15
    int b = pid >> 4, pos0 = (pid & 15) * 64;
    int n0 = blockIdx.y * 64;
    int tid = threadIdx.x, lane = tid & 63, w = tid >> 6;
    int cl = lane & 15, gp = lane >> 4;
    f32x4 acc0[4], acc1[4];
#pragma unroll
    for (int nt = 0; nt < 4; nt++)
#pragma unroll
        for (int r = 0; r < 4; r++) { acc0[nt][r] = 0.f; acc1[nt][r] = 0.f; }
    int arow = tid >> 2, akg = tid & 3;
    const bf16x8* A8 = (const bf16x8*)ybf;
    const bf16x8* B8 = (const bf16x8*)Wprojt;
    size_t rowe0 = (size_t)(b * 2) * 1024 + pos0 + arow;
    for (int ks = 0; ks < 512; ks += 32) {
        __syncthreads();
        int kc = (ks >> 3) + akg;
        bf16x8 va0 = A8[rowe0 * 64 + kc];
        bf16x8 va1 = A8[(rowe0 + 1024) * 64 + kc];
        bf16x8 vb  = B8[(size_t)(n0 + arow) * 64 + kc];
        *(bf16x8*)&As0[arow * 40 + akg * 8] = va0;
        *(bf16x8*)&As1[arow * 40 + akg * 8] = va1;
        *(bf16x8*)&Bs[arow * 40 + akg * 8]  = vb;
        __syncthreads();
        bf16x8 a0 = *(const bf16x8*)&As0[(w * 16 + cl) * 40 + gp * 8];
        bf16x8 a1 = *(const bf16x8*)&As1[(w * 16 + cl) * 40 + gp * 8];
#pragma unroll
        for (int nt = 0; nt < 4; nt++) {
            bf16x8 bfr = *(const bf16x8*)&Bs[(nt * 16 + cl) * 40 + gp * 8];
            acc0[nt] = mfma16(a0, bfr, acc0[nt]);
            acc1[nt] = mfma16(a1, bfr, acc1[nt]);
        }
    }
#pragma unroll
    for (int r = 0; r < 4; r++) {
        int pos = pos0 + w * 16 + gp * 4 + r;
        int bk = b * 1024 + pos;
        int t = idx[bk];
        float wv = wsel[bk], g0 = gate[bk * 2], g1 = gate[bk * 2 + 1];
        float* orow = out + ((size_t)(b * 2048 + t)) * 512;
#pragma unroll
        for (int nt = 0; nt < 4; nt++) {
            int col = n0 + nt * 16 + cl;
            orow[col] += wv * (g0 * acc0[nt][r] + g1 * acc1[nt][r]);
        }
    }
}

// 10. BCE loss from precomputed predictor logits. single block.
__global__ void k_loss(const float* __restrict__ pl, const int* __restrict__ mask,
                       float* __restrict__ outloss) {
    __shared__ float red[16];
    int tid = threadIdx.x;                // 1024
    float s = 0.f;
#pragma unroll
    for (int j = 0; j < 4; j++) {
        int i = tid * 4 + j;
        float p = pl[i];
        float tgt = (float)mask[i];
        s += fmaxf(p, 0.f) - p * tgt + log1pf(__expf(-fabsf(p)));
    }
    for (int mm = 1; mm < 64; mm <<= 1) s += __shfl_xor(s, mm);
    int lane = tid & 63, w = tid >> 6;
    if (lane == 0) red[w] = s;
    __syncthreads();
    if (tid == 0) {
        float t = 0.f;
        for (int q = 0; q < 16; q++) t += red[q];
        outloss[0] = t * (1.0f / 4096.0f);
    }
}

// ---------------------------------------------------------------------------
extern "C" void kernel_launch(void* const* d_in, const int* in_sizes, int n_in,
                              void* d_out, int out_size, void* d_ws, size_t ws_size,
                              hipStream_t stream) {
    const float* x        = (const float*)d_in[0];
    const float* W_router = (const float*)d_in[1];
    const float* W_q      = (const float*)d_in[2];
    const float* W_kv     = (const float*)d_in[3];
    const float* W_proj   = (const float*)d_in[4];
    const float* ln_w     = (const float*)d_in[5];
    const float* W_gate   = (const float*)d_in[6];
    const float* W_pred   = (const float*)d_in[7];

    char* ws = (char*)d_ws;
    float*    logits = (float*)   (ws + OFF_LOGITS);
    float*    pl     = (float*)   (ws + OFF_PL);
    int*      mask   = (int*)     (ws + OFF_MASK);
    int*      posmap = (int*)     (ws + OFF_POSMAP);
    int*      idx    = (int*)     (ws + OFF_IDX);
    float*    wsel   = (float*)   (ws + OFF_WSEL);
    float*    gate   = (float*)   (ws + OFF_GATE);
    uint16_t* selbf  = (uint16_t*)(ws + OFF_SELBF);
    uint16_t* Wqkvt  = (uint16_t*)(ws + OFF_WQKVT);
    uint16_t* Wprojt = (uint16_t*)(ws + OFF_WPROJT);
    float*    qkvraw = (float*)   (ws + OFF_QKVRAW);
    uint16_t* po     = (uint16_t*)(ws + OFF_PO);
    float2*   pml    = (float2*)  (ws + OFF_PML);
    uint16_t* Qh     = (uint16_t*)(ws + OFF_QH);
    uint16_t* Kh     = (uint16_t*)(ws + OFF_KH);
    uint16_t* Vt     = (uint16_t*)(ws + OFF_VT);
    uint16_t* ybf    = (uint16_t*)(ws + OFF_YBF);
    float*    out    = (float*)d_out;

    k_castw      <<<2368, 256, 0, stream>>>(W_q, W_kv, W_proj, Wqkvt, Wprojt,
                                            (const float4*)x, (float4*)out);
    k_router     <<<1024, 256, 0, stream>>>(x, W_router, W_pred, logits, pl);
    k_rank       <<<1024, 256, 0, stream>>>(logits, mask);
    k_select     <<<2, 1024, 0, stream>>>(logits, mask, idx, wsel, posmap);
    k_gather_gate<<<2048, 256, 0, stream>>>(x, idx, W_gate, selbf, gate);
    k_gemm       <<<dim3(16, 16), 256, 0, stream>>>(selbf, Wqkvt, qkvraw, 2048, 2048, 512);
    k_norm_rope  <<<2048, 256, 0, stream>>>(qkvraw, ln_w, Qh, Kh);
    k_vt         <<<256, 256, 0, stream>>>(qkvraw, Vt);
    k_attn       <<<2048, 256, 0, stream>>>(Qh, Kh, Vt, po, pml);
    k_combine    <<<4096, 256, 0, stream>>>(po, pml, ybf);
    k_projc      <<<dim3(32, 8), 256, 0, stream>>>(ybf, Wprojt, idx, wsel, gate, out);
    k_loss       <<<1, 1024, 0, stream>>>(pl, mask, out + 2097152);
}

// Round 7
// 110.575 us; speedup vs baseline: 1.4629x; 1.0188x over previous
//
#include <hip/hip_runtime.h>
#include <cstdint>

// ---------------------------------------------------------------------------
// MoDBlock: B=2, T=2048, C=512, E=2, NH=8, hs=64, k=1024 (hardcoded).
// Output: out [B,T,C] f32 (2097152) + loss (1).
// ---------------------------------------------------------------------------

#define DI __device__ __forceinline__

typedef __bf16 bf16x8 __attribute__((ext_vector_type(8)));
typedef float  f32x4  __attribute__((ext_vector_type(4)));
typedef short  s16x4  __attribute__((ext_vector_type(4)));
typedef short  s16x8  __attribute__((ext_vector_type(8)));

DI uint16_t f2bf(float f) {
    union { float f; uint32_t u; } v; v.f = f;
    uint32_t u = v.u;
    uint32_t r = (u + 0x7FFFu + ((u >> 16) & 1u)) >> 16;   // RNE; finite inputs only
    return (uint16_t)r;
}
DI float bf2f(uint32_t lo16) {
    union { uint32_t u; float f; } v; v.u = lo16 << 16; return v.f;
}

DI f32x4 mfma16(bf16x8 a, bf16x8 b, f32x4 c) {
    return __builtin_amdgcn_mfma_f32_16x16x32_bf16(a, b, c, 0, 0, 0);
}
DI f32x4 mfma_k16(s16x4 a, s16x4 b, f32x4 c) {
    return __builtin_amdgcn_mfma_f32_16x16x16bf16_1k(a, b, c, 0, 0, 0);
}

// ---- workspace layout (bytes) ----
constexpr size_t OFF_LOGITS = 0;                                // 4096 f32
constexpr size_t OFF_PL     = OFF_LOGITS + 4096 * 4;            // 4096 f32
constexpr size_t OFF_MASK   = OFF_PL     + 4096 * 4;            // 4096 int
constexpr size_t OFF_POSMAP = OFF_MASK   + 4096 * 4;            // 4096 int
constexpr size_t OFF_IDX    = OFF_POSMAP + 4096 * 4;            // 2048 int
constexpr size_t OFF_WSEL   = OFF_IDX    + 2048 * 4;            // 2048 f32
constexpr size_t OFF_GATE   = OFF_WSEL   + 2048 * 4;            // 2048*2 f32
constexpr size_t OFF_SELBF  = OFF_GATE   + 4096 * 4;            // 2048*512 bf16
constexpr size_t OFF_WQKVT  = OFF_SELBF  + 2048 * 512 * 2;      // [2048][512] bf16
constexpr size_t OFF_WPROJT = OFF_WQKVT  + 2048 * 512 * 2;      // [512][512] bf16
constexpr size_t OFF_QKVRAW = OFF_WPROJT + 512 * 512 * 2;       // 2048*2048 f32 (16.78MB)
constexpr size_t OFF_QH     = OFF_QKVRAW + (size_t)2048 * 2048 * 4; // [B,E,NH,k,64] bf16
constexpr size_t OFF_KH     = OFF_QH     + (size_t)2097152 * 2;     // [B,NH,k,64] bf16 (pre-scaled 1/8)
constexpr size_t OFF_VT     = OFF_KH     + (size_t)1048576 * 2;     // [B,NH,64,k] bf16 (kv-swizzled)
constexpr size_t OFF_YBF    = OFF_VT     + (size_t)1048576 * 2;     // [B,E,k,512] bf16

// ---------------------------------------------------------------------------
// 1. router logits (f64 accum, top-k boundary safety) + predictor logits.
__global__ void k_router(const float* __restrict__ x, const float* __restrict__ wr,
                         const float* __restrict__ wp,
                         float* __restrict__ logits, float* __restrict__ pl) {
    int wid  = (blockIdx.x * blockDim.x + threadIdx.x) >> 6;
    int lane = threadIdx.x & 63;
    if (wid >= 4096) return;
    const float* xr = x + (size_t)wid * 512;
    double s = 0.0; float sp = 0.f;
#pragma unroll
    for (int j = 0; j < 8; j++) {
        int c = lane + 64 * j;
        float xv = xr[c];
        s  += (double)xv * (double)wr[c];
        sp += xv * wp[c];
    }
    for (int m = 1; m < 64; m <<= 1) { s += __shfl_xor(s, m); sp += __shfl_xor(sp, m); }
    if (lane == 0) { logits[wid] = (float)s; pl[wid] = sp; }
}

// 2. rank: count of strictly-greater (or equal with smaller index) -> mask
__global__ void k_rank(const float* __restrict__ logits, int* __restrict__ mask) {
    int wid  = (blockIdx.x * blockDim.x + threadIdx.x) >> 6;
    int lane = threadIdx.x & 63;
    if (wid >= 4096) return;
    int b = wid >> 11, t = wid & 2047;
    const float* lb = logits + b * 2048;
    float v = lb[t];
    int cnt = 0;
    for (int j = 0; j < 32; j++) {
        int tp = lane + 64 * j;
        float lv = lb[tp];
        bool pred = (lv > v) || (lv == v && tp < t);
        cnt += __popcll(__ballot(pred));
    }
    if (lane == 0) mask[wid] = (cnt < 1024) ? 1 : 0;
}

// 3. wave-scan selection: idx (temporal order), wsel, posmap. 1 block/batch.
__global__ void k_select(const float* __restrict__ logits, const int* __restrict__ mask,
                         int* __restrict__ idx, float* __restrict__ wsel,
                         int* __restrict__ posmap) {
    __shared__ int wsum[16], woff[16];
    int b = blockIdx.x, tid = threadIdx.x, lane = tid & 63, w = tid >> 6;
    int t0 = tid * 2, t1 = tid * 2 + 1;
    int m0 = mask[b * 2048 + t0], m1 = mask[b * 2048 + t1];
    int s = m0 + m1;
    int sc = s;
    for (int off = 1; off < 64; off <<= 1) {
        int v = __shfl_up(sc, off);
        if (lane >= off) sc += v;
    }
    if (lane == 63) wsum[w] = sc;
    __syncthreads();
    if (tid < 16) {
        int acc = 0;
        for (int j = 0; j < tid; j++) acc += wsum[j];
        woff[tid] = acc;
    }
    __syncthreads();
    int excl = woff[w] + sc - s;
    int p0 = excl, p1 = excl + m0;
    if (m0) {
        idx[b * 1024 + p0] = t0;
        float v = logits[b * 2048 + t0];
        wsel[b * 1024 + p0] = 1.f / (1.f + __expf(-v));
    }
    posmap[b * 2048 + t0] = m0 ? p0 : -1;
    if (m1) {
        idx[b * 1024 + p1] = t1;
        float v = logits[b * 2048 + t1];
        wsel[b * 1024 + p1] = 1.f / (1.f + __expf(-v));
    }
    posmap[b * 2048 + t1] = m1 ? p1 : -1;
}

// 4. weight transpose+cast via LDS 64x64 tile (blocks 0..319) + x->out copy (320..2367)
__global__ __launch_bounds__(256) void k_castw(const float* __restrict__ Wq,
                                               const float* __restrict__ Wkv,
                                               const float* __restrict__ Wp,
                                               uint16_t* __restrict__ Wqkvt,
                                               uint16_t* __restrict__ Wprojt,
                                               const float4* __restrict__ xsrc,
                                               float4* __restrict__ outdst) {
    __shared__ float tile[64][65];
    int blk = blockIdx.x, tid = threadIdx.x;
    if (blk >= 320) {                  // copy x -> out (524288 float4)
        int j = (blk - 320) * 256 + tid;
        outdst[j] = xsrc[j];
        return;
    }
    const float* src; uint16_t* dst; int n0, c0, ldn;
    if (blk < 256) {                   // qkv: dest [2048][512]
        int tn = blk & 31, tc = blk >> 5;
        n0 = tn * 64; c0 = tc * 64; ldn = 1024;
        if (n0 < 1024) { src = Wq; } else { src = Wkv; n0 -= 1024; }
        dst = Wqkvt + (size_t)(tn * 64) * 512 + c0;
    } else {                           // proj: dest [512][512]
        int j = blk - 256; int tn = j & 7, tc = j >> 3;
        n0 = tn * 64; c0 = tc * 64; ldn = 512;
        src = Wp; dst = Wprojt + (size_t)n0 * 512 + c0;
    }
    int nl = tid & 63, cb = tid >> 6;
#pragma unroll
    for (int p = 0; p < 16; p++) {
        int cl_ = p * 4 + cb;
        tile[cl_][nl] = src[(size_t)(c0 + cl_) * ldn + n0 + nl];
    }
    __syncthreads();
    int cp = tid & 31, nb = tid >> 5;
#pragma unroll
    for (int p = 0; p < 8; p++) {
        int nl2 = p * 8 + nb;
        uint32_t pk = (uint32_t)f2bf(tile[cp * 2][nl2]) |
                      ((uint32_t)f2bf(tile[cp * 2 + 1][nl2]) << 16);
        *(uint32_t*)&dst[(size_t)nl2 * 512 + cp * 2] = pk;
    }
}

// 5. gather selected rows -> bf16, gate = softmax(sel @ W_gate)
__global__ void k_gather_gate(const float* __restrict__ x, const int* __restrict__ idx,
                              const float* __restrict__ Wg,
                              uint16_t* __restrict__ selbf, float* __restrict__ gate) {
    __shared__ float red0[4], red1[4];
    int blk = blockIdx.x; int b = blk >> 10;
    int tid = threadIdx.x, lane = tid & 63, w = tid >> 6;
    int t = idx[blk];
    const float* xr = x + ((size_t)b * 2048 + t) * 512;
    int c = tid * 2;
    float v0 = xr[c], v1 = xr[c + 1];
    uint32_t pk = (uint32_t)f2bf(v0) | ((uint32_t)f2bf(v1) << 16);
    ((uint32_t*)(selbf + (size_t)blk * 512))[tid] = pk;
    float g0 = v0 * Wg[c * 2]     + v1 * Wg[(c + 1) * 2];
    float g1 = v0 * Wg[c * 2 + 1] + v1 * Wg[(c + 1) * 2 + 1];
    for (int m = 1; m < 64; m <<= 1) { g0 += __shfl_xor(g0, m); g1 += __shfl_xor(g1, m); }
    if (lane == 0) { red0[w] = g0; red1[w] = g1; }
    __syncthreads();
    if (tid == 0) {
        float a = red0[0] + red0[1] + red0[2] + red0[3];
        float bq = red1[0] + red1[1] + red1[2] + red1[3];
        float mx = fmaxf(a, bq);
        float ea = __expf(a - mx), eb = __expf(bq - mx), s = ea + eb;
        gate[blk * 2] = ea / s; gate[blk * 2 + 1] = eb / s;
    }
}

// 6. bf16 MFMA GEMM: C[M,N] f32 = A[M,K]bf16 @ Bt[N,K]^T. 128x128 tile, BK=32.
__global__ __launch_bounds__(256) void k_gemm(const uint16_t* __restrict__ A,
                                              const uint16_t* __restrict__ Bt,
                                              float* __restrict__ Cc,
                                              int M, int N, int Kd) {
    __shared__ uint16_t As[128 * 40], Bs[128 * 40];
    int tid = threadIdx.x, lane = tid & 63, w = tid >> 6;
    int m0 = blockIdx.x * 128, n0 = blockIdx.y * 128;
    int wr = (w >> 1) * 64, wc = (w & 1) * 64;
    f32x4 acc[4][4];
#pragma unroll
    for (int mt = 0; mt < 4; mt++)
#pragma unroll
        for (int nt = 0; nt < 4; nt++)
#pragma unroll
            for (int r = 0; r < 4; r++) acc[mt][nt][r] = 0.f;
    int arow = tid >> 2, akg = tid & 3;
    int K8 = Kd >> 3;
    const bf16x8* A8 = (const bf16x8*)A;
    const bf16x8* B8 = (const bf16x8*)Bt;
    for (int ks = 0; ks < Kd; ks += 32) {
        __syncthreads();
        int kc = (ks >> 3) + akg;
        bf16x8 va0 = A8[(size_t)(m0 + arow) * K8 + kc];
        bf16x8 va1 = A8[(size_t)(m0 + arow + 64) * K8 + kc];
        bf16x8 vb0 = B8[(size_t)(n0 + arow) * K8 + kc];
        bf16x8 vb1 = B8[(size_t)(n0 + arow + 64) * K8 + kc];
        *(bf16x8*)&As[arow * 40 + akg * 8] = va0;
        *(bf16x8*)&As[(arow + 64) * 40 + akg * 8] = va1;
        *(bf16x8*)&Bs[arow * 40 + akg * 8] = vb0;
        *(bf16x8*)&Bs[(arow + 64) * 40 + akg * 8] = vb1;
        __syncthreads();
        bf16x8 af[4], bfr[4];
#pragma unroll
        for (int t = 0; t < 4; t++) {
            af[t]  = *(const bf16x8*)&As[(wr + t * 16 + (lane & 15)) * 40 + (lane >> 4) * 8];
            bfr[t] = *(const bf16x8*)&Bs[(wc + t * 16 + (lane & 15)) * 40 + (lane >> 4) * 8];
        }
#pragma unroll
        for (int mt = 0; mt < 4; mt++)
#pragma unroll
            for (int nt = 0; nt < 4; nt++)
                acc[mt][nt] = mfma16(af[mt], bfr[nt], acc[mt][nt]);
    }
    int r0 = (lane >> 4) * 4, cl = lane & 15;
#pragma unroll
    for (int mt = 0; mt < 4; mt++)
#pragma unroll
        for (int nt = 0; nt < 4; nt++)
#pragma unroll
            for (int r = 0; r < 4; r++) {
                int row = m0 + wr + mt * 16 + r0 + r;
                int col = n0 + wc + nt * 16 + cl;
                Cc[(size_t)row * N + col] = acc[mt][nt][r];
            }
}

// 7. RMSNorm + RoPE -> head-layout bf16 Q and K (K pre-scaled by 1/8)
__global__ void k_norm_rope(const float* __restrict__ qkv, const float* __restrict__ lnw,
                            uint16_t* __restrict__ Qh, uint16_t* __restrict__ Kh) {
    __shared__ float red[4];
    int blk = blockIdx.x; int b = blk >> 10, i = blk & 1023;
    int tid = threadIdx.x, lane = tid & 63, w = tid >> 6;
    const float* row = qkv + (size_t)blk * 2048;
    int c0 = tid * 2;
    int d0 = c0 & 63, head = c0 >> 6;
    int j0 = d0 & 31, j1 = (d0 + 1) & 31;
    const float LN1E4_64 = 0.14391156831212787f;   // ln(10000)/64
    float fi = (float)i;
    float ang0 = fi * __expf(-(float)(4 * j0 + 1) * LN1E4_64);
    float ang1 = fi * __expf(-(float)(4 * j1 + 1) * LN1E4_64);
    float c_0 = cosf(ang0), s_0 = sinf(ang0);
    float c_1 = cosf(ang1), s_1 = sinf(ang1);
    float g0 = lnw[c0], g1 = lnw[c0 + 1];
    for (int which = 0; which < 3; which++) {        // q(e=0), q(e=1), k
        int off = which * 512;
        float u0 = row[off + c0], u1 = row[off + c0 + 1];
        float ss = u0 * u0 + u1 * u1;
        for (int m = 1; m < 64; m <<= 1) ss += __shfl_xor(ss, m);
        __syncthreads();
        if (lane == 0) red[w] = ss;
        __syncthreads();
        float tot = red[0] + red[1] + red[2] + red[3];
        float rinv = rsqrtf(tot * (1.0f / 512.0f) + 1e-6f);
        float n0 = u0 * rinv * g0, n1 = u1 * rinv * g1;
        float r0 = n0 * c_0 - n1 * s_0;              // even dim
        float r1 = n1 * c_1 + n0 * s_1;              // odd dim (different angle!)
        if (which < 2) {
            uint32_t pk = (uint32_t)f2bf(r0) | ((uint32_t)f2bf(r1) << 16);
            uint16_t* dstp = Qh + ((size_t)((b * 2 + which) * 8 + head) * 1024 + i) * 64 + d0;
            *(uint32_t*)dstp = pk;
        } else {                                     // K: fold 1/sqrt(hs)
            uint32_t pk = (uint32_t)f2bf(r0 * 0.125f) | ((uint32_t)f2bf(r1 * 0.125f) << 16);
            uint16_t* dstp = Kh + ((size_t)(b * 8 + head) * 1024 + i) * 64 + d0;
            *(uint32_t*)dstp = pk;
        }
    }
}

// 7b. V transpose: qkvraw cols 1536.. -> Vt[bh][64][swz(1024)] bf16, coalesced both sides
__global__ __launch_bounds__(256) void k_vt(const float* __restrict__ qkv,
                                            uint16_t* __restrict__ Vt) {
    __shared__ float tile[64][65];
    int bh = blockIdx.x >> 4, kt = blockIdx.x & 15;  // 16 bh x 16 kv-tiles
    int b = bh >> 3, h = bh & 7;
    int tid = threadIdx.x;
    int r = tid >> 2, cg = tid & 3;                  // load phase: row r, col group cg
    const float* srow = qkv + ((size_t)(b * 1024 + kt * 64 + r)) * 2048 + 1536 + h * 64 + cg * 16;
#pragma unroll
    for (int p = 0; p < 4; p++) {
        float4 v = *(const float4*)(srow + p * 4);
        tile[r][cg * 16 + p * 4 + 0] = v.x;
        tile[r][cg * 16 + p * 4 + 1] = v.y;
        tile[r][cg * 16 + p * 4 + 2] = v.z;
        tile[r][cg * 16 + p * 4 + 3] = v.w;
    }
    __syncthreads();
    int d = tid >> 2, kg = tid & 3;                  // store phase: dim d, kv group
    int t4 = kg;                                     // i_local = t4*16 + g*4 + j
    uint16_t* drow = Vt + ((size_t)(bh * 64 + d)) * 1024 + kt * 64;
#pragma unroll
    for (int g = 0; g < 4; g++) {
        uint16_t pk[4];
#pragma unroll
        for (int j = 0; j < 4; j++) pk[j] = f2bf(tile[t4 * 16 + g * 4 + j][d]);
        *(uint2*)&drow[g * 16 + t4 * 4] = *(const uint2*)pk;   // swz: i' = g*16 + t*4 + j
    }
}

// 8. causal flash attention. block=(qb desc, inst), 8 waves = 4 q-groups x 2 KV-splits.
//    Fixed-shift softmax p = exp(s-8): mathematically shift-exact, no overflow for
//    |s| <= 64; no online max, no in-loop cross-lane ops; splits combine by plain
//    addition via LDS. Swapped QK^T (K pre-scaled 1/8); PV from swizzled V.
__global__ __launch_bounds__(512, 2) void k_attn(const uint16_t* __restrict__ Qh,
                                                 const uint16_t* __restrict__ Kh,
                                                 const uint16_t* __restrict__ Vt,
                                                 uint16_t* __restrict__ ybf) {
    __shared__ float cb[4][64][17];
    int blk = blockIdx.x;
    int qb = 15 - (blk >> 5);          // big q-tiles first
    int inst = blk & 31;               // ((b*2+e)*8+h)
    int h = inst & 7, b = inst >> 4;
    int tid = threadIdx.x, lane = tid & 63, w = tid >> 6;
    int wq = w & 3, ws = w >> 2;       // q-group, kv-split
    int qw = qb * 64 + wq * 16;
    const uint16_t* Qb = Qh + ((size_t)inst * 1024 + qw) * 64;
    const uint16_t* Kb = Kh + (size_t)(b * 8 + h) * 1024 * 64;
    const uint16_t* Vb = Vt + (size_t)(b * 8 + h) * 64 * 1024;
    int cl = lane & 15, gp = lane >> 4;
    bf16x8 qf0 = *(const bf16x8*)&Qb[cl * 64 + gp * 8];
    bf16x8 qf1 = *(const bf16x8*)&Qb[cl * 64 + 32 + gp * 8];
    f32x4 o[4];
#pragma unroll
    for (int dt = 0; dt < 4; dt++)
#pragma unroll
        for (int r = 0; r < 4; r++) o[dt][r] = 0.f;
    float ls = 0.f;
    int qa = qw + cl;
    const float L2E = 1.44269504f;     // log2(e)
    const float SH  = -11.5415603f;    // -8*log2(e)

    for (int jt = ws * 64; jt <= qw; jt += 128) {
        f32x4 sv[4];
#pragma unroll
        for (int t = 0; t < 4; t++)
#pragma unroll
            for (int r = 0; r < 4; r++) sv[t][r] = 0.f;
#pragma unroll
        for (int t = 0; t < 4; t++) {
            const uint16_t* kr = &Kb[(size_t)(jt + t * 16 + cl) * 64 + gp * 8];
            bf16x8 k0 = *(const bf16x8*)kr;
            bf16x8 k1 = *(const bf16x8*)(kr + 32);
            sv[t] = mfma16(k0, qf0, sv[t]);
            sv[t] = mfma16(k1, qf1, sv[t]);
        }
        // V loads issued early (latency hides under exp/pack)
        s16x8 vv0[4], vv1[4];
#pragma unroll
        for (int dt = 0; dt < 4; dt++) {
            const uint16_t* vrow = &Vb[(size_t)(dt * 16 + cl) * 1024 + jt + gp * 16];
            vv0[dt] = *(const s16x8*)vrow;
            vv1[dt] = *(const s16x8*)(vrow + 8);
        }
        bool bnd = (jt + 63 > qw);
        s16x4 pb[4];
#pragma unroll
        for (int t = 0; t < 4; t++) {
            union { s16x4 s4; __bf16 bf[4]; } pu;
#pragma unroll
            for (int r = 0; r < 4; r++) {
                float p = exp2f(fmaf(sv[t][r], L2E, SH));   // exp(s-8)
                if (bnd) {
                    int kv = jt + t * 16 + gp * 4 + r;
                    p = (kv <= qa) ? p : 0.f;
                }
                ls += p;
                pu.bf[r] = (__bf16)p;
            }
            pb[t] = pu.s4;
        }
#pragma unroll
        for (int dt = 0; dt < 4; dt++) {
            s16x4 a0 = __builtin_shufflevector(vv0[dt], vv0[dt], 0, 1, 2, 3);
            s16x4 a1 = __builtin_shufflevector(vv0[dt], vv0[dt], 4, 5, 6, 7);
            s16x4 a2 = __builtin_shufflevector(vv1[dt], vv1[dt], 0, 1, 2, 3);
            s16x4 a3 = __builtin_shufflevector(vv1[dt], vv1[dt], 4, 5, 6, 7);
            o[dt] = mfma_k16(a0, pb[0], o[dt]);
            o[dt] = mfma_k16(a1, pb[1], o[dt]);
            o[dt] = mfma_k16(a2, pb[2], o[dt]);
            o[dt] = mfma_k16(a3, pb[3], o[dt]);
        }
    }
    // finish ls: sum across the 4 gp groups (q column cl)
    ls += __shfl_xor(ls, 16);
    ls += __shfl_xor(ls, 32);
    // combine the two splits: plain addition (same softmax shift)
    if (ws == 1) {
#pragma unroll
        for (int dt = 0; dt < 4; dt++)
#pragma unroll
            for (int r = 0; r < 4; r++) cb[wq][lane][dt * 4 + r] = o[dt][r];
        cb[wq][lane][16] = ls;
    }
    __syncthreads();
    if (ws == 0) {
        float lst = ls + cb[wq][lane][16];
        float inv = 1.f / lst;
        // ybf row base: be = inst>>3  (FIX: was inst*1024 -> OOB scatter)
        uint16_t* yb = ybf + ((size_t)((inst >> 3) * 1024 + qw)) * 512 + h * 64;
#pragma unroll
        for (int dt = 0; dt < 4; dt++) {
            uint16_t pk[4];
#pragma unroll
            for (int r = 0; r < 4; r++)
                pk[r] = f2bf((o[dt][r] + cb[wq][lane][dt * 4 + r]) * inv);
            *(uint2*)&yb[(size_t)cl * 512 + dt * 16 + gp * 4] = *(const uint2*)pk;
        }
    }
}

// 9. fused proj-GEMM + gated combine + scatter-add into out.
__global__ __launch_bounds__(256) void k_projc(const uint16_t* __restrict__ ybf,
                                               const uint16_t* __restrict__ Wprojt,
                                               const int* __restrict__ idx,
                                               const float* __restrict__ wsel,
                                               const float* __restrict__ gate,
                                               float* __restrict__ out) {
    __shared__ uint16_t As0[64 * 40], As1[64 * 40], Bs[64 * 40];
    int pid = blockIdx.x;              // 32: b = pid>>4, pt = pid&15
    int b = pid >> 4, pos0 = (pid & 15) * 64;
    int n0 = blockIdx.y * 64;
    int tid = threadIdx.x, lane = tid & 63, w = tid >> 6;
    int cl = lane & 15, gp = lane >> 4;
    f32x4 acc0[4], acc1[4];
#pragma unroll
    for (int nt = 0; nt < 4; nt++)
#pragma unroll
        for (int r = 0; r < 4; r++) { acc0[nt][r] = 0.f; acc1[nt][r] = 0.f; }
    int arow = tid >> 2, akg = tid & 3;
    const bf16x8* A8 = (const bf16x8*)ybf;
    const bf16x8* B8 = (const bf16x8*)Wprojt;
    size_t rowe0 = (size_t)(b * 2) * 1024 + pos0 + arow;
    for (int ks = 0; ks < 512; ks += 32) {
        __syncthreads();
        int kc = (ks >> 3) + akg;
        bf16x8 va0 = A8[rowe0 * 64 + kc];
        bf16x8 va1 = A8[(rowe0 + 1024) * 64 + kc];
        bf16x8 vb  = B8[(size_t)(n0 + arow) * 64 + kc];
        *(bf16x8*)&As0[arow * 40 + akg * 8] = va0;
        *(bf16x8*)&As1[arow * 40 + akg * 8] = va1;
        *(bf16x8*)&Bs[arow * 40 + akg * 8]  = vb;
        __syncthreads();
        bf16x8 a0 = *(const bf16x8*)&As0[(w * 16 + cl) * 40 + gp * 8];
        bf16x8 a1 = *(const bf16x8*)&As1[(w * 16 + cl) * 40 + gp * 8];
#pragma unroll
        for (int nt = 0; nt < 4; nt++) {
            bf16x8 bfr = *(const bf16x8*)&Bs[(nt * 16 + cl) * 40 + gp * 8];
            acc0[nt] = mfma16(a0, bfr, acc0[nt]);
            acc1[nt] = mfma16(a1, bfr, acc1[nt]);
        }
    }
#pragma unroll
    for (int r = 0; r < 4; r++) {
        int pos = pos0 + w * 16 + gp * 4 + r;
        int bk = b * 1024 + pos;
        int t = idx[bk];
        float wv = wsel[bk], g0 = gate[bk * 2], g1 = gate[bk * 2 + 1];
        float* orow = out + ((size_t)(b * 2048 + t)) * 512;
#pragma unroll
        for (int nt = 0; nt < 4; nt++) {
            int col = n0 + nt * 16 + cl;
            orow[col] += wv * (g0 * acc0[nt][r] + g1 * acc1[nt][r]);
        }
    }
}

// 10. BCE loss from precomputed predictor logits. single block.
__global__ void k_loss(const float* __restrict__ pl, const int* __restrict__ mask,
                       float* __restrict__ outloss) {
    __shared__ float red[16];
    int tid = threadIdx.x;                // 1024
    float s = 0.f;
#pragma unroll
    for (int j = 0; j < 4; j++) {
        int i = tid * 4 + j;
        float p = pl[i];
        float tgt = (float)mask[i];
        s += fmaxf(p, 0.f) - p * tgt + log1pf(__expf(-fabsf(p)));
    }
    for (int mm = 1; mm < 64; mm <<= 1) s += __shfl_xor(s, mm);
    int lane = tid & 63, w = tid >> 6;
    if (lane == 0) red[w] = s;
    __syncthreads();
    if (tid == 0) {
        float t = 0.f;
        for (int q = 0; q < 16; q++) t += red[q];
        outloss[0] = t * (1.0f / 4096.0f);
    }
}

// ---------------------------------------------------------------------------
extern "C" void kernel_launch(void* const* d_in, const int* in_sizes, int n_in,
                              void* d_out, int out_size, void* d_ws, size_t ws_size,
                              hipStream_t stream) {
    const float* x        = (const float*)d_in[0];
    const float* W_router = (const float*)d_in[1];
    const float* W_q      = (const float*)d_in[2];
    const float* W_kv     = (const float*)d_in[3];
    const float* W_proj   = (const float*)d_in[4];
    const float* ln_w     = (const float*)d_in[5];
    const float* W_gate   = (const float*)d_in[6];
    const float* W_pred   = (const float*)d_in[7];

    char* ws = (char*)d_ws;
    float*    logits = (float*)   (ws + OFF_LOGITS);
    float*    pl     = (float*)   (ws + OFF_PL);
    int*      mask   = (int*)     (ws + OFF_MASK);
    int*      posmap = (int*)     (ws + OFF_POSMAP);
    int*      idx    = (int*)     (ws + OFF_IDX);
    float*    wsel   = (float*)   (ws + OFF_WSEL);
    float*    gate   = (float*)   (ws + OFF_GATE);
    uint16_t* selbf  = (uint16_t*)(ws + OFF_SELBF);
    uint16_t* Wqkvt  = (uint16_t*)(ws + OFF_WQKVT);
    uint16_t* Wprojt = (uint16_t*)(ws + OFF_WPROJT);
    float*    qkvraw = (float*)   (ws + OFF_QKVRAW);
    uint16_t* Qh     = (uint16_t*)(ws + OFF_QH);
    uint16_t* Kh     = (uint16_t*)(ws + OFF_KH);
    uint16_t* Vt     = (uint16_t*)(ws + OFF_VT);
    uint16_t* ybf    = (uint16_t*)(ws + OFF_YBF);
    float*    out    = (float*)d_out;

    k_castw      <<<2368, 256, 0, stream>>>(W_q, W_kv, W_proj, Wqkvt, Wprojt,
                                            (const float4*)x, (float4*)out);
    k_router     <<<1024, 256, 0, stream>>>(x, W_router, W_pred, logits, pl);
    k_rank       <<<1024, 256, 0, stream>>>(logits, mask);
    k_select     <<<2, 1024, 0, stream>>>(logits, mask, idx, wsel, posmap);
    k_gather_gate<<<2048, 256, 0, stream>>>(x, idx, W_gate, selbf, gate);
    k_gemm       <<<dim3(16, 16), 256, 0, stream>>>(selbf, Wqkvt, qkvraw, 2048, 2048, 512);
    k_norm_rope  <<<2048, 256, 0, stream>>>(qkvraw, ln_w, Qh, Kh);
    k_vt         <<<256, 256, 0, stream>>>(qkvraw, Vt);
    k_attn       <<<512, 512, 0, stream>>>(Qh, Kh, Vt, ybf);
    k_projc      <<<dim3(32, 8), 256, 0, stream>>>(ybf, Wprojt, idx, wsel, gate, out);
    k_loss       <<<1, 1024, 0, stream>>>(pl, mask, out + 2097152);
}

// Round 8
// 99.933 us; speedup vs baseline: 1.6187x; 1.1065x over previous
//
#include <hip/hip_runtime.h>
#include <cstdint>

// ---------------------------------------------------------------------------
// MoDBlock: B=2, T=2048, C=512, E=2, NH=8, hs=64, k=1024 (hardcoded).
// Output: out [B,T,C] f32 (2097152) + loss (1).
// ---------------------------------------------------------------------------

#define DI __device__ __forceinline__

typedef __bf16 bf16x8 __attribute__((ext_vector_type(8)));
typedef float  f32x4  __attribute__((ext_vector_type(4)));
typedef short  s16x4  __attribute__((ext_vector_type(4)));
typedef short  s16x8  __attribute__((ext_vector_type(8)));

DI uint16_t f2bf(float f) {
    union { float f; uint32_t u; } v; v.f = f;
    uint32_t u = v.u;
    uint32_t r = (u + 0x7FFFu + ((u >> 16) & 1u)) >> 16;   // RNE; finite inputs only
    return (uint16_t)r;
}
DI float bf2f(uint32_t lo16) {
    union { uint32_t u; float f; } v; v.u = lo16 << 16; return v.f;
}

DI f32x4 mfma16(bf16x8 a, bf16x8 b, f32x4 c) {
    return __builtin_amdgcn_mfma_f32_16x16x32_bf16(a, b, c, 0, 0, 0);
}
DI f32x4 mfma_k16(s16x4 a, s16x4 b, f32x4 c) {
    return __builtin_amdgcn_mfma_f32_16x16x16bf16_1k(a, b, c, 0, 0, 0);
}

// ---- workspace layout (bytes) ----
constexpr size_t OFF_LOGITS = 0;                                // 4096 f32
constexpr size_t OFF_PL     = OFF_LOGITS + 4096 * 4;            // 4096 f32
constexpr size_t OFF_MASK   = OFF_PL     + 4096 * 4;            // 4096 int
constexpr size_t OFF_POSMAP = OFF_MASK   + 4096 * 4;            // 4096 int
constexpr size_t OFF_IDX    = OFF_POSMAP + 4096 * 4;            // 2048 int
constexpr size_t OFF_WSEL   = OFF_IDX    + 2048 * 4;            // 2048 f32
constexpr size_t OFF_GATE   = OFF_WSEL   + 2048 * 4;            // 2048*2 f32
constexpr size_t OFF_SELBF  = OFF_GATE   + 4096 * 4;            // 2048*512 bf16
constexpr size_t OFF_WQKVT  = OFF_SELBF  + 2048 * 512 * 2;      // [2048][512] bf16
constexpr size_t OFF_WPROJT = OFF_WQKVT  + 2048 * 512 * 2;      // [512][512] bf16
constexpr size_t OFF_QKVRAW = OFF_WPROJT + 512 * 512 * 2;       // 2048*2048 f32 (16.78MB)
constexpr size_t OFF_QH     = OFF_QKVRAW + (size_t)2048 * 2048 * 4; // [B,E,NH,k,64] bf16
constexpr size_t OFF_KH     = OFF_QH     + (size_t)2097152 * 2;     // [B,NH,k,64] bf16 (pre-scaled 1/8)
constexpr size_t OFF_VT     = OFF_KH     + (size_t)1048576 * 2;     // [B,NH,64,k] bf16 (kv-swizzled)
constexpr size_t OFF_YBF    = OFF_VT     + (size_t)1048576 * 2;     // [B,E,k,512] bf16

// ---------------------------------------------------------------------------
// 1. router logits (f64 accum, top-k boundary safety) + predictor logits.
__global__ void k_router(const float* __restrict__ x, const float* __restrict__ wr,
                         const float* __restrict__ wp,
                         float* __restrict__ logits, float* __restrict__ pl) {
    int wid  = (blockIdx.x * blockDim.x + threadIdx.x) >> 6;
    int lane = threadIdx.x & 63;
    if (wid >= 4096) return;
    const float* xr = x + (size_t)wid * 512;
    double s = 0.0; float sp = 0.f;
#pragma unroll
    for (int j = 0; j < 8; j++) {
        int c = lane + 64 * j;
        float xv = xr[c];
        s  += (double)xv * (double)wr[c];
        sp += xv * wp[c];
    }
    for (int m = 1; m < 64; m <<= 1) { s += __shfl_xor(s, m); sp += __shfl_xor(sp, m); }
    if (lane == 0) { logits[wid] = (float)s; pl[wid] = sp; }
}

// 2. rank: count of strictly-greater (or equal with smaller index) -> mask
__global__ void k_rank(const float* __restrict__ logits, int* __restrict__ mask) {
    int wid  = (blockIdx.x * blockDim.x + threadIdx.x) >> 6;
    int lane = threadIdx.x & 63;
    if (wid >= 4096) return;
    int b = wid >> 11, t = wid & 2047;
    const float* lb = logits + b * 2048;
    float v = lb[t];
    int cnt = 0;
    for (int j = 0; j < 32; j++) {
        int tp = lane + 64 * j;
        float lv = lb[tp];
        bool pred = (lv > v) || (lv == v && tp < t);
        cnt += __popcll(__ballot(pred));
    }
    if (lane == 0) mask[wid] = (cnt < 1024) ? 1 : 0;
}

// 3. wave-scan selection: idx (temporal order), wsel, posmap. 1 block/batch.
__global__ void k_select(const float* __restrict__ logits, const int* __restrict__ mask,
                         int* __restrict__ idx, float* __restrict__ wsel,
                         int* __restrict__ posmap) {
    __shared__ int wsum[16], woff[16];
    int b = blockIdx.x, tid = threadIdx.x, lane = tid & 63, w = tid >> 6;
    int t0 = tid * 2, t1 = tid * 2 + 1;
    int m0 = mask[b * 2048 + t0], m1 = mask[b * 2048 + t1];
    int s = m0 + m1;
    int sc = s;
    for (int off = 1; off < 64; off <<= 1) {
        int v = __shfl_up(sc, off);
        if (lane >= off) sc += v;
    }
    if (lane == 63) wsum[w] = sc;
    __syncthreads();
    if (tid < 16) {
        int acc = 0;
        for (int j = 0; j < tid; j++) acc += wsum[j];
        woff[tid] = acc;
    }
    __syncthreads();
    int excl = woff[w] + sc - s;
    int p0 = excl, p1 = excl + m0;
    if (m0) {
        idx[b * 1024 + p0] = t0;
        float v = logits[b * 2048 + t0];
        wsel[b * 1024 + p0] = 1.f / (1.f + __expf(-v));
    }
    posmap[b * 2048 + t0] = m0 ? p0 : -1;
    if (m1) {
        idx[b * 1024 + p1] = t1;
        float v = logits[b * 2048 + t1];
        wsel[b * 1024 + p1] = 1.f / (1.f + __expf(-v));
    }
    posmap[b * 2048 + t1] = m1 ? p1 : -1;
}

// 4. weight transpose+cast via LDS 64x64 tile (blocks 0..319) + x->out copy (320..2367)
__global__ __launch_bounds__(256) void k_castw(const float* __restrict__ Wq,
                                               const float* __restrict__ Wkv,
                                               const float* __restrict__ Wp,
                                               uint16_t* __restrict__ Wqkvt,
                                               uint16_t* __restrict__ Wprojt,
                                               const float4* __restrict__ xsrc,
                                               float4* __restrict__ outdst) {
    __shared__ float tile[64][65];
    int blk = blockIdx.x, tid = threadIdx.x;
    if (blk >= 320) {                  // copy x -> out (524288 float4)
        int j = (blk - 320) * 256 + tid;
        outdst[j] = xsrc[j];
        return;
    }
    const float* src; uint16_t* dst; int n0, c0, ldn;
    if (blk < 256) {                   // qkv: dest [2048][512]
        int tn = blk & 31, tc = blk >> 5;
        n0 = tn * 64; c0 = tc * 64; ldn = 1024;
        if (n0 < 1024) { src = Wq; } else { src = Wkv; n0 -= 1024; }
        dst = Wqkvt + (size_t)(tn * 64) * 512 + c0;
    } else {                           // proj: dest [512][512]
        int j = blk - 256; int tn = j & 7, tc = j >> 3;
        n0 = tn * 64; c0 = tc * 64; ldn = 512;
        src = Wp; dst = Wprojt + (size_t)n0 * 512 + c0;
    }
    int nl = tid & 63, cb = tid >> 6;
#pragma unroll
    for (int p = 0; p < 16; p++) {
        int cl_ = p * 4 + cb;
        tile[cl_][nl] = src[(size_t)(c0 + cl_) * ldn + n0 + nl];
    }
    __syncthreads();
    int cp = tid & 31, nb = tid >> 5;
#pragma unroll
    for (int p = 0; p < 8; p++) {
        int nl2 = p * 8 + nb;
        uint32_t pk = (uint32_t)f2bf(tile[cp * 2][nl2]) |
                      ((uint32_t)f2bf(tile[cp * 2 + 1][nl2]) << 16);
        *(uint32_t*)&dst[(size_t)nl2 * 512 + cp * 2] = pk;
    }
}

// 5. gather selected rows -> bf16, gate = softmax(sel @ W_gate)
__global__ void k_gather_gate(const float* __restrict__ x, const int* __restrict__ idx,
                              const float* __restrict__ Wg,
                              uint16_t* __restrict__ selbf, float* __restrict__ gate) {
    __shared__ float red0[4], red1[4];
    int blk = blockIdx.x; int b = blk >> 10;
    int tid = threadIdx.x, lane = tid & 63, w = tid >> 6;
    int t = idx[blk];
    const float* xr = x + ((size_t)b * 2048 + t) * 512;
    int c = tid * 2;
    float v0 = xr[c], v1 = xr[c + 1];
    uint32_t pk = (uint32_t)f2bf(v0) | ((uint32_t)f2bf(v1) << 16);
    ((uint32_t*)(selbf + (size_t)blk * 512))[tid] = pk;
    float g0 = v0 * Wg[c * 2]     + v1 * Wg[(c + 1) * 2];
    float g1 = v0 * Wg[c * 2 + 1] + v1 * Wg[(c + 1) * 2 + 1];
    for (int m = 1; m < 64; m <<= 1) { g0 += __shfl_xor(g0, m); g1 += __shfl_xor(g1, m); }
    if (lane == 0) { red0[w] = g0; red1[w] = g1; }
    __syncthreads();
    if (tid == 0) {
        float a = red0[0] + red0[1] + red0[2] + red0[3];
        float bq = red1[0] + red1[1] + red1[2] + red1[3];
        float mx = fmaxf(a, bq);
        float ea = __expf(a - mx), eb = __expf(bq - mx), s = ea + eb;
        gate[blk * 2] = ea / s; gate[blk * 2 + 1] = eb / s;
    }
}

// 6. bf16 MFMA GEMM: C[M,N] f32 = A[M,K]bf16 @ Bt[N,K]^T. 128x128 tile, BK=32.
__global__ __launch_bounds__(256) void k_gemm(const uint16_t* __restrict__ A,
                                              const uint16_t* __restrict__ Bt,
                                              float* __restrict__ Cc,
                                              int M, int N, int Kd) {
    __shared__ uint16_t As[128 * 40], Bs[128 * 40];
    int tid = threadIdx.x, lane = tid & 63, w = tid >> 6;
    int m0 = blockIdx.x * 128, n0 = blockIdx.y * 128;
    int wr = (w >> 1) * 64, wc = (w & 1) * 64;
    f32x4 acc[4][4];
#pragma unroll
    for (int mt = 0; mt < 4; mt++)
#pragma unroll
        for (int nt = 0; nt < 4; nt++)
#pragma unroll
            for (int r = 0; r < 4; r++) acc[mt][nt][r] = 0.f;
    int arow = tid >> 2, akg = tid & 3;
    int K8 = Kd >> 3;
    const bf16x8* A8 = (const bf16x8*)A;
    const bf16x8* B8 = (const bf16x8*)Bt;
    for (int ks = 0; ks < Kd; ks += 32) {
        __syncthreads();
        int kc = (ks >> 3) + akg;
        bf16x8 va0 = A8[(size_t)(m0 + arow) * K8 + kc];
        bf16x8 va1 = A8[(size_t)(m0 + arow + 64) * K8 + kc];
        bf16x8 vb0 = B8[(size_t)(n0 + arow) * K8 + kc];
        bf16x8 vb1 = B8[(size_t)(n0 + arow + 64) * K8 + kc];
        *(bf16x8*)&As[arow * 40 + akg * 8] = va0;
        *(bf16x8*)&As[(arow + 64) * 40 + akg * 8] = va1;
        *(bf16x8*)&Bs[arow * 40 + akg * 8] = vb0;
        *(bf16x8*)&Bs[(arow + 64) * 40 + akg * 8] = vb1;
        __syncthreads();
        bf16x8 af[4], bfr[4];
#pragma unroll
        for (int t = 0; t < 4; t++) {
            af[t]  = *(const bf16x8*)&As[(wr + t * 16 + (lane & 15)) * 40 + (lane >> 4) * 8];
            bfr[t] = *(const bf16x8*)&Bs[(wc + t * 16 + (lane & 15)) * 40 + (lane >> 4) * 8];
        }
#pragma unroll
        for (int mt = 0; mt < 4; mt++)
#pragma unroll
            for (int nt = 0; nt < 4; nt++)
                acc[mt][nt] = mfma16(af[mt], bfr[nt], acc[mt][nt]);
    }
    int r0 = (lane >> 4) * 4, cl = lane & 15;
#pragma unroll
    for (int mt = 0; mt < 4; mt++)
#pragma unroll
        for (int nt = 0; nt < 4; nt++)
#pragma unroll
            for (int r = 0; r < 4; r++) {
                int row = m0 + wr + mt * 16 + r0 + r;
                int col = n0 + wc + nt * 16 + cl;
                Cc[(size_t)row * N + col] = acc[mt][nt][r];
            }
}

// 7. RMSNorm + RoPE -> head-layout bf16 Q and K (K pre-scaled by 1/8)
__global__ void k_norm_rope(const float* __restrict__ qkv, const float* __restrict__ lnw,
                            uint16_t* __restrict__ Qh, uint16_t* __restrict__ Kh) {
    __shared__ float red[4];
    int blk = blockIdx.x; int b = blk >> 10, i = blk & 1023;
    int tid = threadIdx.x, lane = tid & 63, w = tid >> 6;
    const float* row = qkv + (size_t)blk * 2048;
    int c0 = tid * 2;
    int d0 = c0 & 63, head = c0 >> 6;
    int j0 = d0 & 31, j1 = (d0 + 1) & 31;
    const float LN1E4_64 = 0.14391156831212787f;   // ln(10000)/64
    float fi = (float)i;
    float ang0 = fi * __expf(-(float)(4 * j0 + 1) * LN1E4_64);
    float ang1 = fi * __expf(-(float)(4 * j1 + 1) * LN1E4_64);
    float c_0 = cosf(ang0), s_0 = sinf(ang0);
    float c_1 = cosf(ang1), s_1 = sinf(ang1);
    float g0 = lnw[c0], g1 = lnw[c0 + 1];
    for (int which = 0; which < 3; which++) {        // q(e=0), q(e=1), k
        int off = which * 512;
        float u0 = row[off + c0], u1 = row[off + c0 + 1];
        float ss = u0 * u0 + u1 * u1;
        for (int m = 1; m < 64; m <<= 1) ss += __shfl_xor(ss, m);
        __syncthreads();
        if (lane == 0) red[w] = ss;
        __syncthreads();
        float tot = red[0] + red[1] + red[2] + red[3];
        float rinv = rsqrtf(tot * (1.0f / 512.0f) + 1e-6f);
        float n0 = u0 * rinv * g0, n1 = u1 * rinv * g1;
        float r0 = n0 * c_0 - n1 * s_0;              // even dim
        float r1 = n1 * c_1 + n0 * s_1;              // odd dim (different angle!)
        if (which < 2) {
            uint32_t pk = (uint32_t)f2bf(r0) | ((uint32_t)f2bf(r1) << 16);
            uint16_t* dstp = Qh + ((size_t)((b * 2 + which) * 8 + head) * 1024 + i) * 64 + d0;
            *(uint32_t*)dstp = pk;
        } else {                                     // K: fold 1/sqrt(hs)
            uint32_t pk = (uint32_t)f2bf(r0 * 0.125f) | ((uint32_t)f2bf(r1 * 0.125f) << 16);
            uint16_t* dstp = Kh + ((size_t)(b * 8 + head) * 1024 + i) * 64 + d0;
            *(uint32_t*)dstp = pk;
        }
    }
}

// 7b. V transpose: qkvraw cols 1536.. -> Vt[bh][64][swz(1024)] bf16, coalesced both sides
__global__ __launch_bounds__(256) void k_vt(const float* __restrict__ qkv,
                                            uint16_t* __restrict__ Vt) {
    __shared__ float tile[64][65];
    int bh = blockIdx.x >> 4, kt = blockIdx.x & 15;  // 16 bh x 16 kv-tiles
    int b = bh >> 3, h = bh & 7;
    int tid = threadIdx.x;
    int r = tid >> 2, cg = tid & 3;                  // load phase: row r, col group cg
    const float* srow = qkv + ((size_t)(b * 1024 + kt * 64 + r)) * 2048 + 1536 + h * 64 + cg * 16;
#pragma unroll
    for (int p = 0; p < 4; p++) {
        float4 v = *(const float4*)(srow + p * 4);
        tile[r][cg * 16 + p * 4 + 0] = v.x;
        tile[r][cg * 16 + p * 4 + 1] = v.y;
        tile[r][cg * 16 + p * 4 + 2] = v.z;
        tile[r][cg * 16 + p * 4 + 3] = v.w;
    }
    __syncthreads();
    int d = tid >> 2, kg = tid & 3;                  // store phase: dim d, kv group
    int t4 = kg;                                     // i_local = t4*16 + g*4 + j
    uint16_t* drow = Vt + ((size_t)(bh * 64 + d)) * 1024 + kt * 64;
#pragma unroll
    for (int g = 0; g < 4; g++) {
        uint16_t pk[4];
#pragma unroll
        for (int j = 0; j < 4; j++) pk[j] = f2bf(tile[t4 * 16 + g * 4 + j][d]);
        *(uint2*)&drow[g * 16 + t4 * 4] = *(const uint2*)pk;   // swz: i' = g*16 + t*4 + j
    }
}

// 8. causal flash attention. block=(qt desc, inst), 8 waves = 2 q-groups x 4 KV-splits.
//    QBLK=32 -> grid 1024 = 4 blocks/CU (2048 thr = HW max). Fixed-shift softmax
//    p = exp(s-8) (shift-exact); splits combine by plain addition via LDS.
//    Swapped QK^T (K pre-scaled 1/8); PV from swizzled V.
__global__ __launch_bounds__(512, 2) void k_attn(const uint16_t* __restrict__ Qh,
                                                 const uint16_t* __restrict__ Kh,
                                                 const uint16_t* __restrict__ Vt,
                                                 uint16_t* __restrict__ ybf) {
    __shared__ float cb[3][2][64][17];
    int blk = blockIdx.x;
    int qt = 31 - (blk >> 5);          // big q-tiles first
    int inst = blk & 31;               // ((b*2+e)*8+h)
    int h = inst & 7, b = inst >> 4;
    int tid = threadIdx.x, lane = tid & 63, w = tid >> 6;
    int wq = w & 1, ws = w >> 1;       // q-group (2), kv-split (4)
    int qw = qt * 32 + wq * 16;
    const uint16_t* Qb = Qh + ((size_t)inst * 1024 + qw) * 64;
    const uint16_t* Kb = Kh + (size_t)(b * 8 + h) * 1024 * 64;
    const uint16_t* Vb = Vt + (size_t)(b * 8 + h) * 64 * 1024;
    int cl = lane & 15, gp = lane >> 4;
    bf16x8 qf0 = *(const bf16x8*)&Qb[cl * 64 + gp * 8];
    bf16x8 qf1 = *(const bf16x8*)&Qb[cl * 64 + 32 + gp * 8];
    f32x4 o[4];
#pragma unroll
    for (int dt = 0; dt < 4; dt++)
#pragma unroll
        for (int r = 0; r < 4; r++) o[dt][r] = 0.f;
    float ls = 0.f;
    int qa = qw + cl;
    const float L2E = 1.44269504f;     // log2(e)
    const float SH  = -11.5415603f;    // -8*log2(e)

    for (int jt = ws * 64; jt <= qw; jt += 256) {
        f32x4 sv[4];
#pragma unroll
        for (int t = 0; t < 4; t++)
#pragma unroll
            for (int r = 0; r < 4; r++) sv[t][r] = 0.f;
#pragma unroll
        for (int t = 0; t < 4; t++) {
            const uint16_t* kr = &Kb[(size_t)(jt + t * 16 + cl) * 64 + gp * 8];
            bf16x8 k0 = *(const bf16x8*)kr;
            bf16x8 k1 = *(const bf16x8*)(kr + 32);
            sv[t] = mfma16(k0, qf0, sv[t]);
            sv[t] = mfma16(k1, qf1, sv[t]);
        }
        // V loads issued early (latency hides under exp/pack)
        s16x8 vv0[4], vv1[4];
#pragma unroll
        for (int dt = 0; dt < 4; dt++) {
            const uint16_t* vrow = &Vb[(size_t)(dt * 16 + cl) * 1024 + jt + gp * 16];
            vv0[dt] = *(const s16x8*)vrow;
            vv1[dt] = *(const s16x8*)(vrow + 8);
        }
        bool bnd = (jt + 63 > qw);
        s16x4 pb[4];
#pragma unroll
        for (int t = 0; t < 4; t++) {
            union { s16x4 s4; __bf16 bf[4]; } pu;
#pragma unroll
            for (int r = 0; r < 4; r++) {
                float p = exp2f(fmaf(sv[t][r], L2E, SH));   // exp(s-8)
                if (bnd) {
                    int kv = jt + t * 16 + gp * 4 + r;
                    p = (kv <= qa) ? p : 0.f;
                }
                ls += p;
                pu.bf[r] = (__bf16)p;
            }
            pb[t] = pu.s4;
        }
#pragma unroll
        for (int dt = 0; dt < 4; dt++) {
            s16x4 a0 = __builtin_shufflevector(vv0[dt], vv0[dt], 0, 1, 2, 3);
            s16x4 a1 = __builtin_shufflevector(vv0[dt], vv0[dt], 4, 5, 6, 7);
            s16x4 a2 = __builtin_shufflevector(vv1[dt], vv1[dt], 0, 1, 2, 3);
            s16x4 a3 = __builtin_shufflevector(vv1[dt], vv1[dt], 4, 5, 6, 7);
            o[dt] = mfma_k16(a0, pb[0], o[dt]);
            o[dt] = mfma_k16(a1, pb[1], o[dt]);
            o[dt] = mfma_k16(a2, pb[2], o[dt]);
            o[dt] = mfma_k16(a3, pb[3], o[dt]);
        }
    }
    // finish ls: sum across the 4 gp groups (q column cl)
    ls += __shfl_xor(ls, 16);
    ls += __shfl_xor(ls, 32);
    // combine the four splits: plain addition (same softmax shift)
    if (ws != 0) {
#pragma unroll
        for (int dt = 0; dt < 4; dt++)
#pragma unroll
            for (int r = 0; r < 4; r++) cb[ws - 1][wq][lane][dt * 4 + r] = o[dt][r];
        cb[ws - 1][wq][lane][16] = ls;
    }
    __syncthreads();
    if (ws == 0) {
        float lst = ls + cb[0][wq][lane][16] + cb[1][wq][lane][16] + cb[2][wq][lane][16];
        float inv = 1.f / lst;
        uint16_t* yb = ybf + ((size_t)((inst >> 3) * 1024 + qw)) * 512 + h * 64;
#pragma unroll
        for (int dt = 0; dt < 4; dt++) {
            uint16_t pk[4];
#pragma unroll
            for (int r = 0; r < 4; r++) {
                float v = o[dt][r] + cb[0][wq][lane][dt * 4 + r]
                                   + cb[1][wq][lane][dt * 4 + r]
                                   + cb[2][wq][lane][dt * 4 + r];
                pk[r] = f2bf(v * inv);
            }
            *(uint2*)&yb[(size_t)cl * 512 + dt * 16 + gp * 4] = *(const uint2*)pk;
        }
    }
}

// 9. fused proj-GEMM + gated combine + scatter-add into out.
__global__ __launch_bounds__(256) void k_projc(const uint16_t* __restrict__ ybf,
                                               const uint16_t* __restrict__ Wprojt,
                                               const int* __restrict__ idx,
                                               const float* __restrict__ wsel,
                                               const float* __restrict__ gate,
                                               float* __restrict__ out) {
    __shared__ uint16_t As0[64 * 40], As1[64 * 40], Bs[64 * 40];
    int pid = blockIdx.x;              // 32: b = pid>>4, pt = pid&15
    int b = pid >> 4, pos0 = (pid & 15) * 64;
    int n0 = blockIdx.y * 64;
    int tid = threadIdx.x, lane = tid & 63, w = tid >> 6;
    int cl = lane & 15, gp = lane >> 4;
    f32x4 acc0[4], acc1[4];
#pragma unroll
    for (int nt = 0; nt < 4; nt++)
#pragma unroll
        for (int r = 0; r < 4; r++) { acc0[nt][r] = 0.f; acc1[nt][r] = 0.f; }
    int arow = tid >> 2, akg = tid & 3;
    const bf16x8* A8 = (const bf16x8*)ybf;
    const bf16x8* B8 = (const bf16x8*)Wprojt;
    size_t rowe0 = (size_t)(b * 2) * 1024 + pos0 + arow;
    for (int ks = 0; ks < 512; ks += 32) {
        __syncthreads();
        int kc = (ks >> 3) + akg;
        bf16x8 va0 = A8[rowe0 * 64 + kc];
        bf16x8 va1 = A8[(rowe0 + 1024) * 64 + kc];
        bf16x8 vb  = B8[(size_t)(n0 + arow) * 64 + kc];
        *(bf16x8*)&As0[arow * 40 + akg * 8] = va0;
        *(bf16x8*)&As1[arow * 40 + akg * 8] = va1;
        *(bf16x8*)&Bs[arow * 40 + akg * 8]  = vb;
        __syncthreads();
        bf16x8 a0 = *(const bf16x8*)&As0[(w * 16 + cl) * 40 + gp * 8];
        bf16x8 a1 = *(const bf16x8*)&As1[(w * 16 + cl) * 40 + gp * 8];
#pragma unroll
        for (int nt = 0; nt < 4; nt++) {
            bf16x8 bfr = *(const bf16x8*)&Bs[(nt * 16 + cl) * 40 + gp * 8];
            acc0[nt] = mfma16(a0, bfr, acc0[nt]);
            acc1[nt] = mfma16(a1, bfr, acc1[nt]);
        }
    }
#pragma unroll
    for (int r = 0; r < 4; r++) {
        int pos = pos0 + w * 16 + gp * 4 + r;
        int bk = b * 1024 + pos;
        int t = idx[bk];
        float wv = wsel[bk], g0 = gate[bk * 2], g1 = gate[bk * 2 + 1];
        float* orow = out + ((size_t)(b * 2048 + t)) * 512;
#pragma unroll
        for (int nt = 0; nt < 4; nt++) {
            int col = n0 + nt * 16 + cl;
            orow[col] += wv * (g0 * acc0[nt][r] + g1 * acc1[nt][r]);
        }
    }
}

// 10. BCE loss from precomputed predictor logits. single block.
__global__ void k_loss(const float* __restrict__ pl, const int* __restrict__ mask,
                       float* __restrict__ outloss) {
    __shared__ float red[16];
    int tid = threadIdx.x;                // 1024
    float s = 0.f;
#pragma unroll
    for (int j = 0; j < 4; j++) {
        int i = tid * 4 + j;
        float p = pl[i];
        float tgt = (float)mask[i];
        s += fmaxf(p, 0.f) - p * tgt + log1pf(__expf(-fabsf(p)));
    }
    for (int mm = 1; mm < 64; mm <<= 1) s += __shfl_xor(s, mm);
    int lane = tid & 63, w = tid >> 6;
    if (lane == 0) red[w] = s;
    __syncthreads();
    if (tid == 0) {
        float t = 0.f;
        for (int q = 0; q < 16; q++) t += red[q];
        outloss[0] = t * (1.0f / 4096.0f);
    }
}

// ---------------------------------------------------------------------------
extern "C" void kernel_launch(void* const* d_in, const int* in_sizes, int n_in,
                              void* d_out, int out_size, void* d_ws, size_t ws_size,
                              hipStream_t stream) {
    const float* x        = (const float*)d_in[0];
    const float* W_router = (const float*)d_in[1];
    const float* W_q      = (const float*)d_in[2];
    const float* W_kv     = (const float*)d_in[3];
    const float* W_proj   = (const float*)d_in[4];
    const float* ln_w     = (const float*)d_in[5];
    const float* W_gate   = (const float*)d_in[6];
    const float* W_pred   = (const float*)d_in[7];

    char* ws = (char*)d_ws;
    float*    logits = (float*)   (ws + OFF_LOGITS);
    float*    pl     = (float*)   (ws + OFF_PL);
    int*      mask   = (int*)     (ws + OFF_MASK);
    int*      posmap = (int*)     (ws + OFF_POSMAP);
    int*      idx    = (int*)     (ws + OFF_IDX);
    float*    wsel   = (float*)   (ws + OFF_WSEL);
    float*    gate   = (float*)   (ws + OFF_GATE);
    uint16_t* selbf  = (uint16_t*)(ws + OFF_SELBF);
    uint16_t* Wqkvt  = (uint16_t*)(ws + OFF_WQKVT);
    uint16_t* Wprojt = (uint16_t*)(ws + OFF_WPROJT);
    float*    qkvraw = (float*)   (ws + OFF_QKVRAW);
    uint16_t* Qh     = (uint16_t*)(ws + OFF_QH);
    uint16_t* Kh     = (uint16_t*)(ws + OFF_KH);
    uint16_t* Vt     = (uint16_t*)(ws + OFF_VT);
    uint16_t* ybf    = (uint16_t*)(ws + OFF_YBF);
    float*    out    = (float*)d_out;

    k_castw      <<<2368, 256, 0, stream>>>(W_q, W_kv, W_proj, Wqkvt, Wprojt,
                                            (const float4*)x, (float4*)out);
    k_router     <<<1024, 256, 0, stream>>>(x, W_router, W_pred, logits, pl);
    k_rank       <<<1024, 256, 0, stream>>>(logits, mask);
    k_select     <<<2, 1024, 0, stream>>>(logits, mask, idx, wsel, posmap);
    k_gather_gate<<<2048, 256, 0, stream>>>(x, idx, W_gate, selbf, gate);
    k_gemm       <<<dim3(16, 16), 256, 0, stream>>>(selbf, Wqkvt, qkvraw, 2048, 2048, 512);
    k_norm_rope  <<<2048, 256, 0, stream>>>(qkvraw, ln_w, Qh, Kh);
    k_vt         <<<256, 256, 0, stream>>>(qkvraw, Vt);
    k_attn       <<<1024, 512, 0, stream>>>(Qh, Kh, Vt, ybf);
    k_projc      <<<dim3(32, 8), 256, 0, stream>>>(ybf, Wprojt, idx, wsel, gate, out);
    k_loss       <<<1, 1024, 0, stream>>>(pl, mask, out + 2097152);
}

// Round 9
// 91.711 us; speedup vs baseline: 1.7638x; 1.0897x over previous
//
#include <hip/hip_runtime.h>
#include <cstdint>

// ---------------------------------------------------------------------------
// MoDBlock: B=2, T=2048, C=512, E=2, NH=8, hs=64, k=1024 (hardcoded).
// Output: out [B,T,C] f32 (2097152) + loss (1).
// ---------------------------------------------------------------------------

#define DI __device__ __forceinline__

typedef __bf16 bf16x8 __attribute__((ext_vector_type(8)));
typedef float  f32x4  __attribute__((ext_vector_type(4)));
typedef short  s16x4  __attribute__((ext_vector_type(4)));
typedef short  s16x8  __attribute__((ext_vector_type(8)));

DI uint16_t f2bf(float f) {
    union { float f; uint32_t u; } v; v.f = f;
    uint32_t u = v.u;
    uint32_t r = (u + 0x7FFFu + ((u >> 16) & 1u)) >> 16;   // RNE; finite inputs only
    return (uint16_t)r;
}

DI f32x4 mfma16(bf16x8 a, bf16x8 b, f32x4 c) {
    return __builtin_amdgcn_mfma_f32_16x16x32_bf16(a, b, c, 0, 0, 0);
}
DI f32x4 mfma_k16(s16x4 a, s16x4 b, f32x4 c) {
    return __builtin_amdgcn_mfma_f32_16x16x16bf16_1k(a, b, c, 0, 0, 0);
}
DI void gload16(const void* g, void* l) {       // async 16B/lane global->LDS
    __builtin_amdgcn_global_load_lds(
        (const __attribute__((address_space(1))) uint32_t*)g,
        (__attribute__((address_space(3))) uint32_t*)l, 16, 0, 0);
}

// ---- workspace layout (bytes) ----
constexpr size_t OFF_LOGITS = 0;                                // 4096 f32
constexpr size_t OFF_PL     = OFF_LOGITS + 4096 * 4;            // 4096 f32
constexpr size_t OFF_MASK   = OFF_PL     + 4096 * 4;            // 4096 int
constexpr size_t OFF_POSMAP = OFF_MASK   + 4096 * 4;            // 4096 int
constexpr size_t OFF_IDX    = OFF_POSMAP + 4096 * 4;            // 2048 int
constexpr size_t OFF_WSEL   = OFF_IDX    + 2048 * 4;            // 2048 f32
constexpr size_t OFF_GATE   = OFF_WSEL   + 2048 * 4;            // 2048*2 f32
constexpr size_t OFF_SELBF  = OFF_GATE   + 4096 * 4;            // 2048*512 bf16
constexpr size_t OFF_WQKVT  = OFF_SELBF  + 2048 * 512 * 2;      // [2048][512] bf16
constexpr size_t OFF_WPROJT = OFF_WQKVT  + 2048 * 512 * 2;      // [512][512] bf16
constexpr size_t OFF_QKVRAW = OFF_WPROJT + 512 * 512 * 2;       // 2048*2048 f32
constexpr size_t OFF_QH     = OFF_QKVRAW + (size_t)2048 * 2048 * 4; // [B,E,NH,k,64] bf16
constexpr size_t OFF_KH     = OFF_QH     + (size_t)2097152 * 2;     // [B,NH,k,64] bf16 (pre-scaled 1/8)
constexpr size_t OFF_VT     = OFF_KH     + (size_t)1048576 * 2;     // [B,NH,64,k] bf16 (kv-swizzled)
constexpr size_t OFF_YBF    = OFF_VT     + (size_t)1048576 * 2;     // [B,E,k,512] bf16

// ---------------------------------------------------------------------------
// 1. prep: weight transpose+cast (0..319) + x->out copy (320..2367) +
//    router/predictor logits (2368..3391). All independent.
__global__ __launch_bounds__(256) void k_prep(const float* __restrict__ Wq,
                                              const float* __restrict__ Wkv,
                                              const float* __restrict__ Wp,
                                              uint16_t* __restrict__ Wqkvt,
                                              uint16_t* __restrict__ Wprojt,
                                              const float4* __restrict__ xsrc,
                                              float4* __restrict__ outdst,
                                              const float* __restrict__ x,
                                              const float* __restrict__ wr,
                                              const float* __restrict__ wp,
                                              float* __restrict__ logits,
                                              float* __restrict__ pl) {
    __shared__ float tile[64][65];
    int blk = blockIdx.x, tid = threadIdx.x;
    if (blk >= 2368) {                 // router + predictor logits
        int rblk = blk - 2368;
        int wid  = rblk * 4 + (tid >> 6);
        int lane = tid & 63;
        const float* xr = x + (size_t)wid * 512;
        double s = 0.0; float sp = 0.f;
#pragma unroll
        for (int j = 0; j < 8; j++) {
            int c = lane + 64 * j;
            float xv = xr[c];
            s  += (double)xv * (double)wr[c];
            sp += xv * wp[c];
        }
        for (int m = 1; m < 64; m <<= 1) { s += __shfl_xor(s, m); sp += __shfl_xor(sp, m); }
        if (lane == 0) { logits[wid] = (float)s; pl[wid] = sp; }
        return;
    }
    if (blk >= 320) {                  // copy x -> out (524288 float4)
        int j = (blk - 320) * 256 + tid;
        outdst[j] = xsrc[j];
        return;
    }
    const float* src; uint16_t* dst; int n0, c0, ldn;
    if (blk < 256) {                   // qkv: dest [2048][512]
        int tn = blk & 31, tc = blk >> 5;
        n0 = tn * 64; c0 = tc * 64; ldn = 1024;
        if (n0 < 1024) { src = Wq; } else { src = Wkv; n0 -= 1024; }
        dst = Wqkvt + (size_t)(tn * 64) * 512 + c0;
    } else {                           // proj: dest [512][512]
        int j = blk - 256; int tn = j & 7, tc = j >> 3;
        n0 = tn * 64; c0 = tc * 64; ldn = 512;
        src = Wp; dst = Wprojt + (size_t)n0 * 512 + c0;
    }
    int nl = tid & 63, cb = tid >> 6;
#pragma unroll
    for (int p = 0; p < 16; p++) {
        int cl_ = p * 4 + cb;
        tile[cl_][nl] = src[(size_t)(c0 + cl_) * ldn + n0 + nl];
    }
    __syncthreads();
    int cp = tid & 31, nb = tid >> 5;
#pragma unroll
    for (int p = 0; p < 8; p++) {
        int nl2 = p * 8 + nb;
        uint32_t pk = (uint32_t)f2bf(tile[cp * 2][nl2]) |
                      ((uint32_t)f2bf(tile[cp * 2 + 1][nl2]) << 16);
        *(uint32_t*)&dst[(size_t)nl2 * 512 + cp * 2] = pk;
    }
}

// 2. rank: count of strictly-greater (or equal with smaller index) -> mask
__global__ void k_rank(const float* __restrict__ logits, int* __restrict__ mask) {
    int wid  = (blockIdx.x * blockDim.x + threadIdx.x) >> 6;
    int lane = threadIdx.x & 63;
    if (wid >= 4096) return;
    int b = wid >> 11, t = wid & 2047;
    const float* lb = logits + b * 2048;
    float v = lb[t];
    int cnt = 0;
    for (int j = 0; j < 32; j++) {
        int tp = lane + 64 * j;
        float lv = lb[tp];
        bool pred = (lv > v) || (lv == v && tp < t);
        cnt += __popcll(__ballot(pred));
    }
    if (lane == 0) mask[wid] = (cnt < 1024) ? 1 : 0;
}

// 3. wave-scan selection: idx (temporal order), wsel, posmap. 1 block/batch.
__global__ void k_select(const float* __restrict__ logits, const int* __restrict__ mask,
                         int* __restrict__ idx, float* __restrict__ wsel,
                         int* __restrict__ posmap) {
    __shared__ int wsum[16], woff[16];
    int b = blockIdx.x, tid = threadIdx.x, lane = tid & 63, w = tid >> 6;
    int t0 = tid * 2, t1 = tid * 2 + 1;
    int m0 = mask[b * 2048 + t0], m1 = mask[b * 2048 + t1];
    int s = m0 + m1;
    int sc = s;
    for (int off = 1; off < 64; off <<= 1) {
        int v = __shfl_up(sc, off);
        if (lane >= off) sc += v;
    }
    if (lane == 63) wsum[w] = sc;
    __syncthreads();
    if (tid < 16) {
        int acc = 0;
        for (int j = 0; j < tid; j++) acc += wsum[j];
        woff[tid] = acc;
    }
    __syncthreads();
    int excl = woff[w] + sc - s;
    int p0 = excl, p1 = excl + m0;
    if (m0) {
        idx[b * 1024 + p0] = t0;
        float v = logits[b * 2048 + t0];
        wsel[b * 1024 + p0] = 1.f / (1.f + __expf(-v));
    }
    posmap[b * 2048 + t0] = m0 ? p0 : -1;
    if (m1) {
        idx[b * 1024 + p1] = t1;
        float v = logits[b * 2048 + t1];
        wsel[b * 1024 + p1] = 1.f / (1.f + __expf(-v));
    }
    posmap[b * 2048 + t1] = m1 ? p1 : -1;
}

// 4. gather selected rows -> bf16, gate = softmax(sel @ W_gate)
__global__ void k_gather_gate(const float* __restrict__ x, const int* __restrict__ idx,
                              const float* __restrict__ Wg,
                              uint16_t* __restrict__ selbf, float* __restrict__ gate) {
    __shared__ float red0[4], red1[4];
    int blk = blockIdx.x; int b = blk >> 10;
    int tid = threadIdx.x, lane = tid & 63, w = tid >> 6;
    int t = idx[blk];
    const float* xr = x + ((size_t)b * 2048 + t) * 512;
    int c = tid * 2;
    float v0 = xr[c], v1 = xr[c + 1];
    uint32_t pk = (uint32_t)f2bf(v0) | ((uint32_t)f2bf(v1) << 16);
    ((uint32_t*)(selbf + (size_t)blk * 512))[tid] = pk;
    float g0 = v0 * Wg[c * 2]     + v1 * Wg[(c + 1) * 2];
    float g1 = v0 * Wg[c * 2 + 1] + v1 * Wg[(c + 1) * 2 + 1];
    for (int m = 1; m < 64; m <<= 1) { g0 += __shfl_xor(g0, m); g1 += __shfl_xor(g1, m); }
    if (lane == 0) { red0[w] = g0; red1[w] = g1; }
    __syncthreads();
    if (tid == 0) {
        float a = red0[0] + red0[1] + red0[2] + red0[3];
        float bq = red1[0] + red1[1] + red1[2] + red1[3];
        float mx = fmaxf(a, bq);
        float ea = __expf(a - mx), eb = __expf(bq - mx), s = ea + eb;
        gate[blk * 2] = ea / s; gate[blk * 2 + 1] = eb / s;
    }
}

// 5. bf16 MFMA GEMM, m97-style async staging: C[M,N] f32 = A[M,K] @ Bt[N,K]^T.
//    128x64 tile, BK=32, global_load_lds width 16, linear LDS (conflict-free b128).
__global__ __launch_bounds__(256) void k_gemm(const uint16_t* __restrict__ A,
                                              const uint16_t* __restrict__ Bt,
                                              float* __restrict__ Cc,
                                              int M, int N, int Kd) {
    __shared__ uint16_t As[128 * 32];   // 8 KB
    __shared__ uint16_t Bs[64 * 32];    // 4 KB
    int tid = threadIdx.x, lane = tid & 63, w = tid >> 6;
    int m0 = blockIdx.x * 128, n0 = blockIdx.y * 64;
    int wr = (w >> 1) * 64, wc = (w & 1) * 32;
    int cl = lane & 15, gp = lane >> 4;
    f32x4 acc[4][2];
#pragma unroll
    for (int mt = 0; mt < 4; mt++)
#pragma unroll
        for (int nt = 0; nt < 2; nt++)
#pragma unroll
            for (int r = 0; r < 4; r++) acc[mt][nt][r] = 0.f;
    int srow = lane >> 2, skc = (lane & 3) * 8;      // staging: lane -> row/4, kcol
    for (int ks = 0; ks < Kd; ks += 32) {
        __syncthreads();
        const uint16_t* ga0 = A + (size_t)(m0 + w * 32 + srow) * Kd + ks + skc;
        gload16(ga0, &As[(w * 32) * 32]);
        gload16(ga0 + (size_t)16 * Kd, &As[(w * 32 + 16) * 32]);
        const uint16_t* gb = Bt + (size_t)(n0 + w * 16 + srow) * Kd + ks + skc;
        gload16(gb, &Bs[(w * 16) * 32]);
        __syncthreads();
        bf16x8 af[4], bfr[2];
#pragma unroll
        for (int t = 0; t < 4; t++)
            af[t] = *(const bf16x8*)&As[(wr + t * 16 + cl) * 32 + gp * 8];
#pragma unroll
        for (int t = 0; t < 2; t++)
            bfr[t] = *(const bf16x8*)&Bs[(wc + t * 16 + cl) * 32 + gp * 8];
#pragma unroll
        for (int mt = 0; mt < 4; mt++)
#pragma unroll
            for (int nt = 0; nt < 2; nt++)
                acc[mt][nt] = mfma16(af[mt], bfr[nt], acc[mt][nt]);
    }
    int r0 = gp * 4;
#pragma unroll
    for (int mt = 0; mt < 4; mt++)
#pragma unroll
        for (int nt = 0; nt < 2; nt++)
#pragma unroll
            for (int r = 0; r < 4; r++) {
                int row = m0 + wr + mt * 16 + r0 + r;
                int col = n0 + wc + nt * 16 + cl;
                Cc[(size_t)row * N + col] = acc[mt][nt][r];
            }
}

// 6. norm_rope (0..2047) + V transpose (2048..2303) merged.
__global__ __launch_bounds__(256) void k_nrv(const float* __restrict__ qkv,
                                             const float* __restrict__ lnw,
                                             uint16_t* __restrict__ Qh,
                                             uint16_t* __restrict__ Kh,
                                             uint16_t* __restrict__ Vt) {
    __shared__ float tile[64][65];
    int blk = blockIdx.x, tid = threadIdx.x;
    if (blk >= 2048) {                 // V transpose, kv-swizzled
        int v = blk - 2048;
        int bh = v >> 4, kt = v & 15;
        int b = bh >> 3, h = bh & 7;
        int r = tid >> 2, cg = tid & 3;
        const float* srow = qkv + ((size_t)(b * 1024 + kt * 64 + r)) * 2048 + 1536 + h * 64 + cg * 16;
#pragma unroll
        for (int p = 0; p < 4; p++) {
            float4 vv = *(const float4*)(srow + p * 4);
            tile[r][cg * 16 + p * 4 + 0] = vv.x;
            tile[r][cg * 16 + p * 4 + 1] = vv.y;
            tile[r][cg * 16 + p * 4 + 2] = vv.z;
            tile[r][cg * 16 + p * 4 + 3] = vv.w;
        }
        __syncthreads();
        int d = tid >> 2, t4 = tid & 3;
        uint16_t* drow = Vt + ((size_t)(bh * 64 + d)) * 1024 + kt * 64;
#pragma unroll
        for (int g = 0; g < 4; g++) {
            uint16_t pk[4];
#pragma unroll
            for (int j = 0; j < 4; j++) pk[j] = f2bf(tile[t4 * 16 + g * 4 + j][d]);
            *(uint2*)&drow[g * 16 + t4 * 4] = *(const uint2*)pk;
        }
        return;
    }
    // RMSNorm + RoPE -> Q (e=0,1) and K (pre-scaled 1/8)
    int b = blk >> 10, i = blk & 1023;
    int lane = tid & 63, w = tid >> 6;
    float* red = &tile[0][0];
    const float* row = qkv + (size_t)blk * 2048;
    int c0 = tid * 2;
    int d0 = c0 & 63, head = c0 >> 6;
    int j0 = d0 & 31, j1 = (d0 + 1) & 31;
    const float LN1E4_64 = 0.14391156831212787f;   // ln(10000)/64
    float fi = (float)i;
    float ang0 = fi * __expf(-(float)(4 * j0 + 1) * LN1E4_64);
    float ang1 = fi * __expf(-(float)(4 * j1 + 1) * LN1E4_64);
    float c_0 = cosf(ang0), s_0 = sinf(ang0);
    float c_1 = cosf(ang1), s_1 = sinf(ang1);
    float g0 = lnw[c0], g1 = lnw[c0 + 1];
    for (int which = 0; which < 3; which++) {        // q(e=0), q(e=1), k
        int off = which * 512;
        float u0 = row[off + c0], u1 = row[off + c0 + 1];
        float ss = u0 * u0 + u1 * u1;
        for (int m = 1; m < 64; m <<= 1) ss += __shfl_xor(ss, m);
        __syncthreads();
        if (lane == 0) red[w] = ss;
        __syncthreads();
        float tot = red[0] + red[1] + red[2] + red[3];
        float rinv = rsqrtf(tot * (1.0f / 512.0f) + 1e-6f);
        float n0 = u0 * rinv * g0, n1 = u1 * rinv * g1;
        float r0 = n0 * c_0 - n1 * s_0;              // even dim
        float r1 = n1 * c_1 + n0 * s_1;              // odd dim (different angle!)
        if (which < 2) {
            uint32_t pk = (uint32_t)f2bf(r0) | ((uint32_t)f2bf(r1) << 16);
            uint16_t* dstp = Qh + ((size_t)((b * 2 + which) * 8 + head) * 1024 + i) * 64 + d0;
            *(uint32_t*)dstp = pk;
        } else {                                     // K: fold 1/sqrt(hs)
            uint32_t pk = (uint32_t)f2bf(r0 * 0.125f) | ((uint32_t)f2bf(r1 * 0.125f) << 16);
            uint16_t* dstp = Kh + ((size_t)(b * 8 + head) * 1024 + i) * 64 + d0;
            *(uint32_t*)dstp = pk;
        }
    }
}

// 7. causal flash attention. block=(qt desc, inst), 8 waves = 2 q-groups x 4 KV-splits.
//    Fixed-shift softmax p = exp(s-8) (shift-exact); splits combine by plain addition
//    via LDS. Swapped QK^T (K pre-scaled 1/8); PV from swizzled V.
__global__ __launch_bounds__(512, 2) void k_attn(const uint16_t* __restrict__ Qh,
                                                 const uint16_t* __restrict__ Kh,
                                                 const uint16_t* __restrict__ Vt,
                                                 uint16_t* __restrict__ ybf) {
    __shared__ float cb[3][2][64][17];
    int blk = blockIdx.x;
    int qt = 31 - (blk >> 5);          // big q-tiles first
    int inst = blk & 31;               // ((b*2+e)*8+h)
    int h = inst & 7, b = inst >> 4;
    int tid = threadIdx.x, lane = tid & 63, w = tid >> 6;
    int wq = w & 1, ws = w >> 1;       // q-group (2), kv-split (4)
    int qw = qt * 32 + wq * 16;
    const uint16_t* Qb = Qh + ((size_t)inst * 1024 + qw) * 64;
    const uint16_t* Kb = Kh + (size_t)(b * 8 + h) * 1024 * 64;
    const uint16_t* Vb = Vt + (size_t)(b * 8 + h) * 64 * 1024;
    int cl = lane & 15, gp = lane >> 4;
    bf16x8 qf0 = *(const bf16x8*)&Qb[cl * 64 + gp * 8];
    bf16x8 qf1 = *(const bf16x8*)&Qb[cl * 64 + 32 + gp * 8];
    f32x4 o[4];
#pragma unroll
    for (int dt = 0; dt < 4; dt++)
#pragma unroll
        for (int r = 0; r < 4; r++) o[dt][r] = 0.f;
    float ls = 0.f;
    int qa = qw + cl;
    const float L2E = 1.44269504f;     // log2(e)
    const float SH  = -11.5415603f;    // -8*log2(e)

    for (int jt = ws * 64; jt <= qw; jt += 256) {
        f32x4 sv[4];
#pragma unroll
        for (int t = 0; t < 4; t++)
#pragma unroll
            for (int r = 0; r < 4; r++) sv[t][r] = 0.f;
#pragma unroll
        for (int t = 0; t < 4; t++) {
            const uint16_t* kr = &Kb[(size_t)(jt + t * 16 + cl) * 64 + gp * 8];
            bf16x8 k0 = *(const bf16x8*)kr;
            bf16x8 k1 = *(const bf16x8*)(kr + 32);
            sv[t] = mfma16(k0, qf0, sv[t]);
            sv[t] = mfma16(k1, qf1, sv[t]);
        }
        // V loads issued early (latency hides under exp/pack)
        s16x8 vv0[4], vv1[4];
#pragma unroll
        for (int dt = 0; dt < 4; dt++) {
            const uint16_t* vrow = &Vb[(size_t)(dt * 16 + cl) * 1024 + jt + gp * 16];
            vv0[dt] = *(const s16x8*)vrow;
            vv1[dt] = *(const s16x8*)(vrow + 8);
        }
        bool bnd = (jt + 63 > qw);
        s16x4 pb[4];
#pragma unroll
        for (int t = 0; t < 4; t++) {
            union { s16x4 s4; __bf16 bf[4]; } pu;
#pragma unroll
            for (int r = 0; r < 4; r++) {
                float p = exp2f(fmaf(sv[t][r], L2E, SH));   // exp(s-8)
                if (bnd) {
                    int kv = jt + t * 16 + gp * 4 + r;
                    p = (kv <= qa) ? p : 0.f;
                }
                ls += p;
                pu.bf[r] = (__bf16)p;
            }
            pb[t] = pu.s4;
        }
#pragma unroll
        for (int dt = 0; dt < 4; dt++) {
            s16x4 a0 = __builtin_shufflevector(vv0[dt], vv0[dt], 0, 1, 2, 3);
            s16x4 a1 = __builtin_shufflevector(vv0[dt], vv0[dt], 4, 5, 6, 7);
            s16x4 a2 = __builtin_shufflevector(vv1[dt], vv1[dt], 0, 1, 2, 3);
            s16x4 a3 = __builtin_shufflevector(vv1[dt], vv1[dt], 4, 5, 6, 7);
            o[dt] = mfma_k16(a0, pb[0], o[dt]);
            o[dt] = mfma_k16(a1, pb[1], o[dt]);
            o[dt] = mfma_k16(a2, pb[2], o[dt]);
            o[dt] = mfma_k16(a3, pb[3], o[dt]);
        }
    }
    ls += __shfl_xor(ls, 16);
    ls += __shfl_xor(ls, 32);
    if (ws != 0) {
#pragma unroll
        for (int dt = 0; dt < 4; dt++)
#pragma unroll
            for (int r = 0; r < 4; r++) cb[ws - 1][wq][lane][dt * 4 + r] = o[dt][r];
        cb[ws - 1][wq][lane][16] = ls;
    }
    __syncthreads();
    if (ws == 0) {
        float lst = ls + cb[0][wq][lane][16] + cb[1][wq][lane][16] + cb[2][wq][lane][16];
        float inv = 1.f / lst;
        uint16_t* yb = ybf + ((size_t)((inst >> 3) * 1024 + qw)) * 512 + h * 64;
#pragma unroll
        for (int dt = 0; dt < 4; dt++) {
            uint16_t pk[4];
#pragma unroll
            for (int r = 0; r < 4; r++) {
                float v = o[dt][r] + cb[0][wq][lane][dt * 4 + r]
                                   + cb[1][wq][lane][dt * 4 + r]
                                   + cb[2][wq][lane][dt * 4 + r];
                pk[r] = f2bf(v * inv);
            }
            *(uint2*)&yb[(size_t)cl * 512 + dt * 16 + gp * 4] = *(const uint2*)pk;
        }
    }
}

// 8. fused proj-GEMM + gated combine; DIRECT store out = x + wv*(g0*y0+g1*y1).
__global__ __launch_bounds__(256) void k_projc(const uint16_t* __restrict__ ybf,
                                               const uint16_t* __restrict__ Wprojt,
                                               const int* __restrict__ idx,
                                               const float* __restrict__ wsel,
                                               const float* __restrict__ gate,
                                               const float* __restrict__ x,
                                               float* __restrict__ out) {
    __shared__ uint16_t As0[64 * 40], As1[64 * 40], Bs[64 * 40];
    int pid = blockIdx.x;              // 32: b = pid>>4, pt = pid&15
    int b = pid >> 4, pos0 = (pid & 15) * 64;
    int n0 = blockIdx.y * 64;
    int tid = threadIdx.x, lane = tid & 63, w = tid >> 6;
    int cl = lane & 15, gp = lane >> 4;
    f32x4 acc0[4], acc1[4];
#pragma unroll
    for (int nt = 0; nt < 4; nt++)
#pragma unroll
        for (int r = 0; r < 4; r++) { acc0[nt][r] = 0.f; acc1[nt][r] = 0.f; }
    int arow = tid >> 2, akg = tid & 3;
    const bf16x8* A8 = (const bf16x8*)ybf;
    const bf16x8* B8 = (const bf16x8*)Wprojt;
    size_t rowe0 = (size_t)(b * 2) * 1024 + pos0 + arow;
    for (int ks = 0; ks < 512; ks += 32) {
        __syncthreads();
        int kc = (ks >> 3) + akg;
        bf16x8 va0 = A8[rowe0 * 64 + kc];
        bf16x8 va1 = A8[(rowe0 + 1024) * 64 + kc];
        bf16x8 vb  = B8[(size_t)(n0 + arow) * 64 + kc];
        *(bf16x8*)&As0[arow * 40 + akg * 8] = va0;
        *(bf16x8*)&As1[arow * 40 + akg * 8] = va1;
        *(bf16x8*)&Bs[arow * 40 + akg * 8]  = vb;
        __syncthreads();
        bf16x8 a0 = *(const bf16x8*)&As0[(w * 16 + cl) * 40 + gp * 8];
        bf16x8 a1 = *(const bf16x8*)&As1[(w * 16 + cl) * 40 + gp * 8];
#pragma unroll
        for (int nt = 0; nt < 4; nt++) {
            bf16x8 bfr = *(const bf16x8*)&Bs[(nt * 16 + cl) * 40 + gp * 8];
            acc0[nt] = mfma16(a0, bfr, acc0[nt]);
            acc1[nt] = mfma16(a1, bfr, acc1[nt]);
        }
    }
#pragma unroll
    for (int r = 0; r < 4; r++) {
        int pos = pos0 + w * 16 + gp * 4 + r;
        int bk = b * 1024 + pos;
        int t = idx[bk];
        float wv = wsel[bk], g0 = gate[bk * 2], g1 = gate[bk * 2 + 1];
        const float* xrow = x + ((size_t)(b * 2048 + t)) * 512;
        float* orow = out + ((size_t)(b * 2048 + t)) * 512;
#pragma unroll
        for (int nt = 0; nt < 4; nt++) {
            int col = n0 + nt * 16 + cl;
            orow[col] = xrow[col] + wv * (g0 * acc0[nt][r] + g1 * acc1[nt][r]);
        }
    }
}

// 9. BCE loss from precomputed predictor logits. single block.
__global__ void k_loss(const float* __restrict__ pl, const int* __restrict__ mask,
                       float* __restrict__ outloss) {
    __shared__ float red[16];
    int tid = threadIdx.x;                // 1024
    float s = 0.f;
#pragma unroll
    for (int j = 0; j < 4; j++) {
        int i = tid * 4 + j;
        float p = pl[i];
        float tgt = (float)mask[i];
        s += fmaxf(p, 0.f) - p * tgt + log1pf(__expf(-fabsf(p)));
    }
    for (int mm = 1; mm < 64; mm <<= 1) s += __shfl_xor(s, mm);
    int lane = tid & 63, w = tid >> 6;
    if (lane == 0) red[w] = s;
    __syncthreads();
    if (tid == 0) {
        float t = 0.f;
        for (int q = 0; q < 16; q++) t += red[q];
        outloss[0] = t * (1.0f / 4096.0f);
    }
}

// ---------------------------------------------------------------------------
extern "C" void kernel_launch(void* const* d_in, const int* in_sizes, int n_in,
                              void* d_out, int out_size, void* d_ws, size_t ws_size,
                              hipStream_t stream) {
    const float* x        = (const float*)d_in[0];
    const float* W_router = (const float*)d_in[1];
    const float* W_q      = (const float*)d_in[2];
    const float* W_kv     = (const float*)d_in[3];
    const float* W_proj   = (const float*)d_in[4];
    const float* ln_w     = (const float*)d_in[5];
    const float* W_gate   = (const float*)d_in[6];
    const float* W_pred   = (const float*)d_in[7];

    char* ws = (char*)d_ws;
    float*    logits = (float*)   (ws + OFF_LOGITS);
    float*    pl     = (float*)   (ws + OFF_PL);
    int*      mask   = (int*)     (ws + OFF_MASK);
    int*      posmap = (int*)     (ws + OFF_POSMAP);
    int*      idx    = (int*)     (ws + OFF_IDX);
    float*    wsel   = (float*)   (ws + OFF_WSEL);
    float*    gate   = (float*)   (ws + OFF_GATE);
    uint16_t* selbf  = (uint16_t*)(ws + OFF_SELBF);
    uint16_t* Wqkvt  = (uint16_t*)(ws + OFF_WQKVT);
    uint16_t* Wprojt = (uint16_t*)(ws + OFF_WPROJT);
    float*    qkvraw = (float*)   (ws + OFF_QKVRAW);
    uint16_t* Qh     = (uint16_t*)(ws + OFF_QH);
    uint16_t* Kh     = (uint16_t*)(ws + OFF_KH);
    uint16_t* Vt     = (uint16_t*)(ws + OFF_VT);
    uint16_t* ybf    = (uint16_t*)(ws + OFF_YBF);
    float*    out    = (float*)d_out;

    k_prep       <<<3392, 256, 0, stream>>>(W_q, W_kv, W_proj, Wqkvt, Wprojt,
                                            (const float4*)x, (float4*)out,
                                            x, W_router, W_pred, logits, pl);
    k_rank       <<<1024, 256, 0, stream>>>(logits, mask);
    k_select     <<<2, 1024, 0, stream>>>(logits, mask, idx, wsel, posmap);
    k_gather_gate<<<2048, 256, 0, stream>>>(x, idx, W_gate, selbf, gate);
    k_gemm       <<<dim3(16, 32), 256, 0, stream>>>(selbf, Wqkvt, qkvraw, 2048, 2048, 512);
    k_nrv        <<<2304, 256, 0, stream>>>(qkvraw, ln_w, Qh, Kh, Vt);
    k_attn       <<<1024, 512, 0, stream>>>(Qh, Kh, Vt, ybf);
    k_projc      <<<dim3(32, 8), 256, 0, stream>>>(ybf, Wprojt, idx, wsel, gate, x, out);
    k_loss       <<<1, 1024, 0, stream>>>(pl, mask, out + 2097152);
}